// Round 1
// baseline (1491.451 us; speedup 1.0000x reference)
//
#include <hip/hip_runtime.h>
#include <math.h>

// Problem: B=2, N=64, D=16.
// Matrices C_{b,n,m,k} = diag(Q_n) T_k diag(K_m), 131072 of them, each 16x16.
// Features per matrix: det (closed form), trace (closed form),
// sum log(sigma+eps) / sigma_min / sigma_max (one-sided Jacobi SVD),
// rho = spectral radius (repeated squaring of T_k diag(Q.K), similarity-equivalent).

#define EPSF 1e-6f

// workspace float offsets (total 987392 floats = 3.95 MB)
#define WS_Q    0         // [2][64][16]            = 2048
#define WS_K    2048      // [2][64][16]            = 2048
#define WS_DETT 4096      // [16]                   = 16 (+pad)
#define WS_V    4352      // [2][64][6][16][16]     = 196608
#define WS_SIGN 200960    // [2][64][64][6][16]     = 786432

// ---------------- Q = X Wq, K = X Wk ----------------
__global__ __launch_bounds__(256) void k_qk(const float* __restrict__ X,
                                            const float* __restrict__ Wk,
                                            const float* __restrict__ Wq,
                                            float* __restrict__ Q,
                                            float* __restrict__ Kout) {
  int t = blockIdx.x * 256 + threadIdx.x;   // exactly 2048 threads
  int i = t & 15, bn = t >> 4;
  const float* x = X + bn * 16;
  float q = 0.f, kk = 0.f;
#pragma unroll
  for (int d = 0; d < 16; ++d) {
    float xv = x[d];
    q  += xv * Wq[d * 16 + i];
    kk += xv * Wk[d * 16 + i];
  }
  Q[t] = q; Kout[t] = kk;
}

// ---------------- det(T_k) via LU with partial pivoting (16 tiny LUs) ----------------
__global__ __launch_bounds__(64) void k_dett(const float* __restrict__ T,
                                             float* __restrict__ detT) {
  __shared__ float A[16][16][16];  // [k][i][j]
  for (int idx = threadIdx.x; idx < 4096; idx += 64) {
    int i = idx >> 8, j = (idx >> 4) & 15, kk = idx & 15;
    A[kk][i][j] = T[idx];          // T[i,j,k] at i*256+j*16+k
  }
  __syncthreads();
  int k = threadIdx.x;
  if (k < 16) {
    float det = 1.0f;
    for (int c = 0; c < 16; ++c) {
      int p = c; float mx = fabsf(A[k][c][c]);
      for (int r = c + 1; r < 16; ++r) {
        float v = fabsf(A[k][r][c]);
        if (v > mx) { mx = v; p = r; }
      }
      if (mx == 0.0f) { det = 0.0f; break; }
      if (p != c) {
        det = -det;
        for (int cc = c; cc < 16; ++cc) {
          float tmp = A[k][c][cc]; A[k][c][cc] = A[k][p][cc]; A[k][p][cc] = tmp;
        }
      }
      float piv = A[k][c][c];
      det *= piv;
      float inv = 1.0f / piv;
      for (int r = c + 1; r < 16; ++r) {
        float f = A[k][r][c] * inv;
        for (int cc = c + 1; cc < 16; ++cc) A[k][r][cc] -= f * A[k][c][cc];
      }
    }
    detT[k] = det;
  }
}

// ---------------- V = einsum('bmd,dskv->bmskv') ----------------
__global__ __launch_bounds__(256) void k_v(const float* __restrict__ X,
                                           const float* __restrict__ Wv,
                                           float* __restrict__ V) {
  int t = blockIdx.x * 256 + threadIdx.x;   // exactly 196608 threads
  int bm = t / 1536; int rem = t - bm * 1536;
  int s = rem >> 8; int kk = (rem >> 4) & 15; int v = rem & 15;
  const float* x = X + bm * 16;
  float acc = 0.f;
#pragma unroll
  for (int d = 0; d < 16; ++d) acc += x[d] * Wv[((d * 6 + s) * 16 + kk) * 16 + v];
  V[t] = acc;
}

// ---------------- SVD features + det + trace ----------------
// 8 lanes per matrix, each lane holds two 16-element columns in registers.
// One-sided Jacobi (Hestenes), Brent-Luk tournament: 15 rounds/sweep, 8 sweeps.
__global__ __launch_bounds__(256) void k_svd(const float* __restrict__ Q,
                                             const float* __restrict__ K,
                                             const float* __restrict__ T,
                                             const float* __restrict__ detT,
                                             float* __restrict__ Sign) {
  int gtid = blockIdx.x * 256 + threadIdx.x;
  int gid = gtid >> 3;          // matrix id, < 131072 exactly
  int l = gtid & 7;             // lane within group
  int k = gid & 15, m = (gid >> 4) & 63, n = (gid >> 10) & 63, b = gid >> 16;
  const float* qrow = Q + (b * 64 + n) * 16;
  const float* krow = K + (b * 64 + m) * 16;

  float qv[16];
#pragma unroll
  for (int i = 0; i < 16; ++i) qv[i] = qrow[i];

  // trace, prod(Q), prod(K) (redundant across the 8 lanes; cached loads)
  float trace = 0.f, pq = 1.f, pk = 1.f;
#pragma unroll
  for (int i = 0; i < 16; ++i) {
    float kv = krow[i];
    pq *= qv[i]; pk *= kv;
    trace += qv[i] * kv * T[i * 272 + k];   // T[i,i,k]
  }
  float det = pq * pk * detT[k];

  // init: lane l owns columns jt=2l, jb=2l+1 of C; C[i][j] = Q_i * T[i,j,k] * K_j
  float t0[16], b0[16];
  int jt = 2 * l, jb = 2 * l + 1;
  float kt = krow[jt], kb = krow[jb];
#pragma unroll
  for (int i = 0; i < 16; ++i) {
    t0[i] = qv[i] * T[i * 256 + jt * 16 + k] * kt;
    b0[i] = qv[i] * T[i * 256 + jb * 16 + k] * kb;
  }

  int lane = threadIdx.x & 63;
  int lm1 = (lane - 1) & 63, lp1 = (lane + 1) & 63;

  for (int sweep = 0; sweep < 8; ++sweep) {
    for (int round = 0; round < 15; ++round) {
      float al = 0.f, be = 0.f, ga = 0.f;
#pragma unroll
      for (int i = 0; i < 16; ++i) {
        al += t0[i] * t0[i];
        be += b0[i] * b0[i];
        ga += t0[i] * b0[i];
      }
      float c = 1.0f, s = 0.0f;
      if (fabsf(ga) > 1e-37f) {
        float zeta = (be - al) / (2.0f * ga);
        float tt = copysignf(1.0f, zeta) / (fabsf(zeta) + sqrtf(1.0f + zeta * zeta));
        c = 1.0f / sqrtf(1.0f + tt * tt);
        s = c * tt;
      }
#pragma unroll
      for (int i = 0; i < 16; ++i) {
        float tn = c * t0[i] - s * b0[i];
        float bn = s * t0[i] + c * b0[i];
        t0[i] = tn; b0[i] = bn;
      }
      // Brent-Luk migration: top shifts right (l0 keeps; l1 <- bot of l-1),
      // bottom shifts left (l7 <- own old top).
#pragma unroll
      for (int i = 0; i < 16; ++i) {
        float tp  = __shfl(t0[i], lm1, 64);
        float bp  = __shfl(b0[i], lm1, 64);
        float bnx = __shfl(b0[i], lp1, 64);
        float ot = t0[i];
        float nt = (l == 0) ? ot : ((l == 1) ? bp : tp);
        float nb = (l == 7) ? ot : bnx;
        t0[i] = nt; b0[i] = nb;
      }
    }
  }

  float nt2 = 0.f, nb2 = 0.f;
#pragma unroll
  for (int i = 0; i < 16; ++i) { nt2 += t0[i] * t0[i]; nb2 += b0[i] * b0[i]; }
  float nu = sqrtf(nt2), nv = sqrtf(nb2);
  float lmin = fminf(nu, nv), lmax = fmaxf(nu, nv);
  float lsum = logf(nu + EPSF) + logf(nv + EPSF);
#pragma unroll
  for (int off = 1; off < 8; off <<= 1) {
    lmin = fminf(lmin, __shfl_xor(lmin, off, 64));
    lmax = fmaxf(lmax, __shfl_xor(lmax, off, 64));
    lsum += __shfl_xor(lsum, off, 64);
  }
  if (l == 0) {
    float* sp = Sign + (((b * 64 + n) * 64 + m) * 6) * 16 + k;  // stride 16 per feature
    sp[0]      = det;    // s=0 det
    sp[16]     = trace;  // s=1 trace
    sp[32]     = lsum;   // s=2 rank_approx
    sp[48]     = lmin;   // s=3 sigma_min
    sp[64]     = lmax;   // s=4 sigma_max
  }
}

// ---------------- rho = spectral radius via repeated squaring ----------------
// eig(C) == eig(T_k * diag(Q.K)).  A_{i+1} = (1/ss_i) * A_i^2,  ss_i = ||A_i||_F^2,
// log rho ~= sum_i log(ss_i) * 2^-(i+1)  (i = 0..J, last term is the final norm).
// 4 lanes per matrix; own 4 columns + accumulators in registers, matrix staged in LDS.
#define RHO_J 14
__global__ __launch_bounds__(128) void k_rho(const float* __restrict__ Q,
                                             const float* __restrict__ K,
                                             const float* __restrict__ T,
                                             float* __restrict__ Sign) {
  __shared__ float Abuf[32][260];   // 260-float stride: 2-way bank aliasing only (free)
  int gtid = blockIdx.x * 128 + threadIdx.x;
  int gid = gtid >> 2;              // matrix id, < 131072 exactly
  int l = threadIdx.x & 3;
  int sg = threadIdx.x >> 2;        // group slot in block, 0..31
  int k = gid & 15, m = (gid >> 4) & 63, n = (gid >> 10) & 63, b = gid >> 16;
  const float* qrow = Q + (b * 64 + n) * 16;
  const float* krow = K + (b * 64 + m) * 16;

  float a[4][16];
#pragma unroll
  for (int jj = 0; jj < 4; ++jj) {
    int j = 4 * l + jj;
    float w = qrow[j] * krow[j];
#pragma unroll
    for (int i = 0; i < 16; ++i) a[jj][i] = T[i * 256 + j * 16 + k] * w;
  }

  float L = 0.0f, wgt = 0.5f;
  for (int it = 0; it <= RHO_J; ++it) {
    float ss = 0.f;
#pragma unroll
    for (int jj = 0; jj < 4; ++jj)
#pragma unroll
      for (int i = 0; i < 16; ++i) ss += a[jj][i] * a[jj][i];
    ss += __shfl_xor(ss, 1, 64);
    ss += __shfl_xor(ss, 2, 64);
    L += logf(ss) * wgt;            // logf(0) = -inf -> rho = 0, correct limit
    wgt *= 0.5f;
    if (it == RHO_J) break;
    float s = (ss > 0.0f) ? (1.0f / ss) : 0.0f;

    // publish own columns (col-major within the group's slot)
#pragma unroll
    for (int jj = 0; jj < 4; ++jj)
#pragma unroll
      for (int i = 0; i < 16; ++i) Abuf[sg][(4 * l + jj) * 16 + i] = a[jj][i];
    __syncthreads();

    float acc[4][16];
#pragma unroll
    for (int jj = 0; jj < 4; ++jj)
#pragma unroll
      for (int i = 0; i < 16; ++i) acc[jj][i] = 0.f;
#pragma unroll
    for (int kk = 0; kk < 16; ++kk) {
      float colk[16];
#pragma unroll
      for (int i = 0; i < 16; ++i) colk[i] = Abuf[sg][kk * 16 + i];  // quad-broadcast
#pragma unroll
      for (int jj = 0; jj < 4; ++jj) {
        float f = a[jj][kk];        // static index (kk unrolled)
#pragma unroll
        for (int i = 0; i < 16; ++i) acc[jj][i] += colk[i] * f;
      }
    }
    __syncthreads();                // protect next iteration's writes
#pragma unroll
    for (int jj = 0; jj < 4; ++jj)
#pragma unroll
      for (int i = 0; i < 16; ++i) a[jj][i] = acc[jj][i] * s;
  }
  float rho = expf(L);
  if (l == 0) Sign[(((b * 64 + n) * 64 + m) * 6 + 5) * 16 + k] = rho;
}

// ---------------- out[b,n,v] = sum_{m,s,k} Sign * V ----------------
__global__ __launch_bounds__(256) void k_out(const float* __restrict__ Sign,
                                             const float* __restrict__ V,
                                             float* __restrict__ out) {
  int t = blockIdx.x * 256 + threadIdx.x;   // exactly 2048
  int v = t & 15; int bn = t >> 4; int b = bn >> 6;
  const float* sp = Sign + bn * (64 * 6 * 16);
  const float* vp = V + b * (64 * 6 * 16 * 16);
  float acc = 0.f;
  for (int m = 0; m < 64; ++m) {
    for (int s = 0; s < 6; ++s) {
#pragma unroll
      for (int kk = 0; kk < 16; ++kk) {
        acc += sp[(m * 6 + s) * 16 + kk] * vp[((m * 6 + s) * 16 + kk) * 16 + v];
      }
    }
  }
  out[t] = acc;
}

extern "C" void kernel_launch(void* const* d_in, const int* in_sizes, int n_in,
                              void* d_out, int out_size, void* d_ws, size_t ws_size,
                              hipStream_t stream) {
  const float* X  = (const float*)d_in[0];
  const float* Wk = (const float*)d_in[1];
  const float* Wq = (const float*)d_in[2];
  const float* T  = (const float*)d_in[3];
  const float* Wv = (const float*)d_in[4];
  float* out = (float*)d_out;
  float* ws = (float*)d_ws;

  float* Q    = ws + WS_Q;
  float* K    = ws + WS_K;
  float* detT = ws + WS_DETT;
  float* V    = ws + WS_V;
  float* Sign = ws + WS_SIGN;

  hipLaunchKernelGGL(k_qk,   dim3(8),    dim3(256), 0, stream, X, Wk, Wq, Q, K);
  hipLaunchKernelGGL(k_dett, dim3(1),    dim3(64),  0, stream, T, detT);
  hipLaunchKernelGGL(k_v,    dim3(768),  dim3(256), 0, stream, X, Wv, V);
  hipLaunchKernelGGL(k_svd,  dim3(4096), dim3(256), 0, stream, Q, K, T, detT, Sign);
  hipLaunchKernelGGL(k_rho,  dim3(4096), dim3(128), 0, stream, Q, K, T, Sign);
  hipLaunchKernelGGL(k_out,  dim3(8),    dim3(256), 0, stream, Sign, V, out);
}

// Round 3
// 787.711 us; speedup vs baseline: 1.8934x; 1.8934x over previous
//
#include <hip/hip_runtime.h>
#include <math.h>

// Problem: B=2, N=64, D=16.
// C_{b,n,m,k} = diag(Q_n) T_k diag(K_m), 131072 16x16 matrices.
// det/trace closed-form; sigma via one-sided Jacobi (Brent-Luk, carried norms);
// rho via normalized repeated squaring of T_k diag(Q.K).

#define EPSF 1e-6f
#define SWEEPS 5
#define RHO_J 12

// workspace float offsets
#define WS_Q    0         // [2][64][16]            = 2048
#define WS_K    2048      // [2][64][16]            = 2048
#define WS_DETT 4096      // [16]
#define WS_V    4352      // [2][64][6][16][16]     = 196608
#define WS_SIGN 200960    // [2][64][64][6][16]     = 786432

__device__ __forceinline__ float bperm(int byteaddr, float v) {
  return __int_as_float(__builtin_amdgcn_ds_bpermute(byteaddr, __float_as_int(v)));
}

// ---------------- Q = X Wq, K = X Wk ----------------
__global__ __launch_bounds__(256) void k_qk(const float* __restrict__ X,
                                            const float* __restrict__ Wk,
                                            const float* __restrict__ Wq,
                                            float* __restrict__ Q,
                                            float* __restrict__ Kout) {
  int t = blockIdx.x * 256 + threadIdx.x;   // exactly 2048 threads
  int i = t & 15, bn = t >> 4;
  const float* x = X + bn * 16;
  float q = 0.f, kk = 0.f;
#pragma unroll
  for (int d = 0; d < 16; ++d) {
    float xv = x[d];
    q  += xv * Wq[d * 16 + i];
    kk += xv * Wk[d * 16 + i];
  }
  Q[t] = q; Kout[t] = kk;
}

// ---------------- det(T_k) via LU with partial pivoting ----------------
__global__ __launch_bounds__(64) void k_dett(const float* __restrict__ T,
                                             float* __restrict__ detT) {
  __shared__ float A[16][16][16];  // [k][i][j]
  for (int idx = threadIdx.x; idx < 4096; idx += 64) {
    int i = idx >> 8, j = (idx >> 4) & 15, kk = idx & 15;
    A[kk][i][j] = T[idx];          // T[i,j,k] at i*256+j*16+k
  }
  __syncthreads();
  int k = threadIdx.x;
  if (k < 16) {
    float det = 1.0f;
    for (int c = 0; c < 16; ++c) {
      int p = c; float mx = fabsf(A[k][c][c]);
      for (int r = c + 1; r < 16; ++r) {
        float v = fabsf(A[k][r][c]);
        if (v > mx) { mx = v; p = r; }
      }
      if (mx == 0.0f) { det = 0.0f; break; }
      if (p != c) {
        det = -det;
        for (int cc = c; cc < 16; ++cc) {
          float tmp = A[k][c][cc]; A[k][c][cc] = A[k][p][cc]; A[k][p][cc] = tmp;
        }
      }
      float piv = A[k][c][c];
      det *= piv;
      float inv = 1.0f / piv;
      for (int r = c + 1; r < 16; ++r) {
        float f = A[k][r][c] * inv;
        for (int cc = c + 1; cc < 16; ++cc) A[k][r][cc] -= f * A[k][c][cc];
      }
    }
    detT[k] = det;
  }
}

// ---------------- V = einsum('bmd,dskv->bmskv') ----------------
__global__ __launch_bounds__(256) void k_v(const float* __restrict__ X,
                                           const float* __restrict__ Wv,
                                           float* __restrict__ V) {
  int t = blockIdx.x * 256 + threadIdx.x;   // exactly 196608 threads
  int bm = t / 1536; int rem = t - bm * 1536;
  int s = rem >> 8; int kk = (rem >> 4) & 15; int v = rem & 15;
  const float* x = X + bm * 16;
  float acc = 0.f;
#pragma unroll
  for (int d = 0; d < 16; ++d) acc += x[d] * Wv[((d * 6 + s) * 16 + kk) * 16 + v];
  V[t] = acc;
}

// ---------------- SVD features + det + trace ----------------
// 8 lanes/matrix, 2 columns/lane in registers. One-sided Jacobi, Brent-Luk.
// Carried squared norms (Rutishauser update), raw ds_bpermute migration.
__global__ __launch_bounds__(256) void k_svd(const float* __restrict__ Q,
                                             const float* __restrict__ K,
                                             const float* __restrict__ T,
                                             const float* __restrict__ detT,
                                             float* __restrict__ Sign) {
  int gtid = blockIdx.x * 256 + threadIdx.x;
  int gid = gtid >> 3;          // matrix id, < 131072
  int l = gtid & 7;
  int k = gid & 15, m = (gid >> 4) & 63, n = (gid >> 10) & 63, b = gid >> 16;
  const float* qrow = Q + (b * 64 + n) * 16;
  const float* krow = K + (b * 64 + m) * 16;

  float qv[16];
#pragma unroll
  for (int i = 0; i < 16; ++i) qv[i] = qrow[i];

  float trace = 0.f, pq = 1.f, pk = 1.f;
#pragma unroll
  for (int i = 0; i < 16; ++i) {
    float kv = krow[i];
    pq *= qv[i]; pk *= kv;
    trace += qv[i] * kv * T[i * 272 + k];   // T[i,i,k]
  }
  float det = pq * pk * detT[k];

  float t0[16], b0[16];
  {
    int jt = 2 * l, jb = 2 * l + 1;
    float kt = krow[jt], kb = krow[jb];
#pragma unroll
    for (int i = 0; i < 16; ++i) {
      t0[i] = qv[i] * T[i * 256 + jt * 16 + k] * kt;
      b0[i] = qv[i] * T[i * 256 + jb * 16 + k] * kb;
    }
  }

  // initial squared column norms (carried exactly through rotations)
  float al = 0.f, be = 0.f;
#pragma unroll
  for (int i = 0; i < 16; ++i) {
    al = fmaf(t0[i], t0[i], al);
    be = fmaf(b0[i], b0[i], be);
  }

  int lane = threadIdx.x & 63;
  int am1 = ((lane - 1) & 63) << 2;  // byte addr for ds_bpermute (hoisted)
  int ap1 = ((lane + 1) & 63) << 2;
  bool l0 = (l == 0), l7 = (l == 7);

  for (int round = 0; round < SWEEPS * 15; ++round) {
    // only the cross dot-product is needed; al/be are carried
    float ga = 0.f;
#pragma unroll
    for (int i = 0; i < 16; ++i) ga = fmaf(t0[i], b0[i], ga);
    float zeta = __fdividef(be - al, 2.0f * ga);
    float tt = __fdividef(copysignf(1.0f, zeta),
                          fabsf(zeta) + sqrtf(fmaf(zeta, zeta, 1.0f)));
    tt = (ga == 0.0f) ? 0.0f : tt;   // kill NaN from 0/0
    float c = rsqrtf(fmaf(tt, tt, 1.0f));
    float s = c * tt, ns = -s;
#pragma unroll
    for (int i = 0; i < 16; ++i) {
      float ti = t0[i], bi = b0[i];
      t0[i] = fmaf(ns, bi, c * ti);
      b0[i] = fmaf(s, ti, c * bi);
    }
    float tg = tt * ga;
    al -= tg; be += tg;              // Rutishauser norm update (exact)

    // Brent-Luk migration: 2 bpermutes + 3 selects per element
#pragma unroll
    for (int i = 0; i < 16; ++i) {
      float st = l0 ? b0[i] : t0[i];   // what lane l sends to (l+1)'s top
      float r1 = bperm(am1, st);
      float r2 = bperm(ap1, b0[i]);
      float ot = t0[i];
      t0[i] = l0 ? ot : r1;
      b0[i] = l7 ? ot : r2;
    }
    {  // migrate the carried norms alongside their columns
      float sa = l0 ? be : al;
      float r1 = bperm(am1, sa);
      float r2 = bperm(ap1, be);
      float oa = al;
      al = l0 ? oa : r1;
      be = l7 ? oa : r2;
    }
  }

  // exact final norms
  float nt2 = 0.f, nb2 = 0.f;
#pragma unroll
  for (int i = 0; i < 16; ++i) {
    nt2 = fmaf(t0[i], t0[i], nt2);
    nb2 = fmaf(b0[i], b0[i], nb2);
  }
  float nu = sqrtf(nt2), nv = sqrtf(nb2);
  float lmin = fminf(nu, nv), lmax = fmaxf(nu, nv);
  float lsum = logf(nu + EPSF) + logf(nv + EPSF);
#pragma unroll
  for (int off = 1; off < 8; off <<= 1) {
    lmin = fminf(lmin, __shfl_xor(lmin, off, 64));
    lmax = fmaxf(lmax, __shfl_xor(lmax, off, 64));
    lsum += __shfl_xor(lsum, off, 64);
  }
  if (l == 0) {
    float* sp = Sign + (((b * 64 + n) * 64 + m) * 6) * 16 + k;
    sp[0]  = det;
    sp[16] = trace;
    sp[32] = lsum;
    sp[48] = lmin;
    sp[64] = lmax;
  }
}

// ---------------- rho = spectral radius via repeated squaring ----------------
__global__ __launch_bounds__(128) void k_rho(const float* __restrict__ Q,
                                             const float* __restrict__ K,
                                             const float* __restrict__ T,
                                             float* __restrict__ Sign) {
  __shared__ float Abuf[32][257];   // stride 257: conflict-free group reads
  int gtid = blockIdx.x * 128 + threadIdx.x;
  int gid = gtid >> 2;              // matrix id, < 131072
  int l = threadIdx.x & 3;
  int sg = threadIdx.x >> 2;
  int k = gid & 15, m = (gid >> 4) & 63, n = (gid >> 10) & 63, b = gid >> 16;
  const float* qrow = Q + (b * 64 + n) * 16;
  const float* krow = K + (b * 64 + m) * 16;

  float a[4][16];
#pragma unroll
  for (int jj = 0; jj < 4; ++jj) {
    int j = 4 * l + jj;
    float w = qrow[j] * krow[j];
#pragma unroll
    for (int i = 0; i < 16; ++i) a[jj][i] = T[i * 256 + j * 16 + k] * w;
  }

  float L = 0.0f, wgt = 0.5f;
  for (int it = 0; it <= RHO_J; ++it) {
    float ss = 0.f;
#pragma unroll
    for (int jj = 0; jj < 4; ++jj)
#pragma unroll
      for (int i = 0; i < 16; ++i) ss = fmaf(a[jj][i], a[jj][i], ss);
    ss += __shfl_xor(ss, 1, 64);
    ss += __shfl_xor(ss, 2, 64);
    L += logf(ss) * wgt;
    wgt *= 0.5f;
    if (it == RHO_J) break;
    float s = (ss > 0.0f) ? (1.0f / ss) : 0.0f;

#pragma unroll
    for (int jj = 0; jj < 4; ++jj)
#pragma unroll
      for (int i = 0; i < 16; ++i) Abuf[sg][(4 * l + jj) * 16 + i] = a[jj][i];
    __syncthreads();

    float acc[4][16];
#pragma unroll
    for (int jj = 0; jj < 4; ++jj)
#pragma unroll
      for (int i = 0; i < 16; ++i) acc[jj][i] = 0.f;
#pragma unroll
    for (int kk = 0; kk < 16; ++kk) {
      float colk[16];
#pragma unroll
      for (int i = 0; i < 16; ++i) colk[i] = Abuf[sg][kk * 16 + i];
#pragma unroll
      for (int jj = 0; jj < 4; ++jj) {
        float f = a[jj][kk];
#pragma unroll
        for (int i = 0; i < 16; ++i) acc[jj][i] = fmaf(colk[i], f, acc[jj][i]);
      }
    }
    __syncthreads();
#pragma unroll
    for (int jj = 0; jj < 4; ++jj)
#pragma unroll
      for (int i = 0; i < 16; ++i) a[jj][i] = acc[jj][i] * s;
  }
  float rho = expf(L);
  if (l == 0) Sign[(((b * 64 + n) * 64 + m) * 6 + 5) * 16 + k] = rho;
}

// ---------------- out[b,n,v] = sum_{m,s,k} Sign * V ----------------
// one block per (b,n); 256 threads = 16 v x 16 m-chunks; LDS tree reduce.
__global__ __launch_bounds__(256) void k_out(const float* __restrict__ Sign,
                                             const float* __restrict__ V,
                                             float* __restrict__ out) {
  __shared__ float red[256];
  int bn = blockIdx.x;              // 0..127
  int b = bn >> 6;
  int t = threadIdx.x;
  int v = t & 15, mc = t >> 4;      // m in [mc*4, mc*4+4)
  const float* sp = Sign + bn * 6144;
  const float* vp = V + b * 98304;
  float acc = 0.f;
  for (int mm = 0; mm < 4; ++mm) {
    int m = mc * 4 + mm;
    const float* sr = sp + m * 96;
    const float* vr = vp + m * 1536 + v;
#pragma unroll
    for (int sk = 0; sk < 96; ++sk) acc = fmaf(sr[sk], vr[sk * 16], acc);
  }
  red[t] = acc;
  __syncthreads();
  for (int off = 128; off >= 16; off >>= 1) {
    if (t < off) red[t] += red[t + off];
    __syncthreads();
  }
  if (t < 16) out[bn * 16 + t] = red[t];
}

extern "C" void kernel_launch(void* const* d_in, const int* in_sizes, int n_in,
                              void* d_out, int out_size, void* d_ws, size_t ws_size,
                              hipStream_t stream) {
  const float* X  = (const float*)d_in[0];
  const float* Wk = (const float*)d_in[1];
  const float* Wq = (const float*)d_in[2];
  const float* T  = (const float*)d_in[3];
  const float* Wv = (const float*)d_in[4];
  float* out = (float*)d_out;
  float* ws = (float*)d_ws;

  float* Q    = ws + WS_Q;
  float* K    = ws + WS_K;
  float* detT = ws + WS_DETT;
  float* V    = ws + WS_V;
  float* Sign = ws + WS_SIGN;

  hipLaunchKernelGGL(k_qk,   dim3(8),    dim3(256), 0, stream, X, Wk, Wq, Q, K);
  hipLaunchKernelGGL(k_dett, dim3(1),    dim3(64),  0, stream, T, detT);
  hipLaunchKernelGGL(k_v,    dim3(768),  dim3(256), 0, stream, X, Wv, V);
  hipLaunchKernelGGL(k_svd,  dim3(4096), dim3(256), 0, stream, Q, K, T, detT, Sign);
  hipLaunchKernelGGL(k_rho,  dim3(4096), dim3(128), 0, stream, Q, K, T, Sign);
  hipLaunchKernelGGL(k_out,  dim3(128),  dim3(256), 0, stream, Sign, V, out);  // FIX: 128 blocks (was 8)
}

// Round 4
// 782.701 us; speedup vs baseline: 1.9055x; 1.0064x over previous
//
#include <hip/hip_runtime.h>
#include <math.h>

// Problem: B=2, N=64, D=16.
// C_{b,n,m,k} = diag(Q_n) T_k diag(K_m), 131072 16x16 matrices.
// det/trace closed-form; sigma via one-sided Jacobi (Brent-Luk, carried norms,
// DPP lane+-1 migration); rho via normalized repeated squaring with quad_perm
// broadcast (no LDS, no barriers).

#define EPSF 1e-6f
#define SWEEPS 6
#define RHO_J 12

// workspace float offsets
#define WS_Q    0         // [2][64][16]            = 2048
#define WS_K    2048      // [2][64][16]            = 2048
#define WS_DETT 4096      // [16]
#define WS_V    4352      // [2][64][6][16][16]     = 196608
#define WS_SIGN 200960    // [2][64][64][6][16]     = 786432

// DPP lane moves (full VALU rate, no LDS pipe).
// row_shr:1 = 0x111 -> lane i gets lane i-1 (within 16-lane row)
// row_shl:1 = 0x101 -> lane i gets lane i+1
template <int CTRL>
__device__ __forceinline__ float dppf(float v) {
  return __int_as_float(__builtin_amdgcn_update_dpp(
      0, __float_as_int(v), CTRL, 0xF, 0xF, true));
}

// ---------------- Q = X Wq, K = X Wk ----------------
__global__ __launch_bounds__(256) void k_qk(const float* __restrict__ X,
                                            const float* __restrict__ Wk,
                                            const float* __restrict__ Wq,
                                            float* __restrict__ Q,
                                            float* __restrict__ Kout) {
  int t = blockIdx.x * 256 + threadIdx.x;   // exactly 2048 threads
  int i = t & 15, bn = t >> 4;
  const float* x = X + bn * 16;
  float q = 0.f, kk = 0.f;
#pragma unroll
  for (int d = 0; d < 16; ++d) {
    float xv = x[d];
    q  += xv * Wq[d * 16 + i];
    kk += xv * Wk[d * 16 + i];
  }
  Q[t] = q; Kout[t] = kk;
}

// ---------------- det(T_k) via LU with partial pivoting ----------------
__global__ __launch_bounds__(64) void k_dett(const float* __restrict__ T,
                                             float* __restrict__ detT) {
  __shared__ float A[16][16][16];  // [k][i][j]
  for (int idx = threadIdx.x; idx < 4096; idx += 64) {
    int i = idx >> 8, j = (idx >> 4) & 15, kk = idx & 15;
    A[kk][i][j] = T[idx];          // T[i,j,k] at i*256+j*16+k
  }
  __syncthreads();
  int k = threadIdx.x;
  if (k < 16) {
    float det = 1.0f;
    for (int c = 0; c < 16; ++c) {
      int p = c; float mx = fabsf(A[k][c][c]);
      for (int r = c + 1; r < 16; ++r) {
        float v = fabsf(A[k][r][c]);
        if (v > mx) { mx = v; p = r; }
      }
      if (mx == 0.0f) { det = 0.0f; break; }
      if (p != c) {
        det = -det;
        for (int cc = c; cc < 16; ++cc) {
          float tmp = A[k][c][cc]; A[k][c][cc] = A[k][p][cc]; A[k][p][cc] = tmp;
        }
      }
      float piv = A[k][c][c];
      det *= piv;
      float inv = 1.0f / piv;
      for (int r = c + 1; r < 16; ++r) {
        float f = A[k][r][c] * inv;
        for (int cc = c + 1; cc < 16; ++cc) A[k][r][cc] -= f * A[k][c][cc];
      }
    }
    detT[k] = det;
  }
}

// ---------------- V = einsum('bmd,dskv->bmskv') ----------------
__global__ __launch_bounds__(256) void k_v(const float* __restrict__ X,
                                           const float* __restrict__ Wv,
                                           float* __restrict__ V) {
  int t = blockIdx.x * 256 + threadIdx.x;   // exactly 196608 threads
  int bm = t / 1536; int rem = t - bm * 1536;
  int s = rem >> 8; int kk = (rem >> 4) & 15; int v = rem & 15;
  const float* x = X + bm * 16;
  float acc = 0.f;
#pragma unroll
  for (int d = 0; d < 16; ++d) acc += x[d] * Wv[((d * 6 + s) * 16 + kk) * 16 + v];
  V[t] = acc;
}

// ---------------- SVD features + det + trace ----------------
// 8 lanes/matrix, 2 columns/lane in registers. One-sided Jacobi, Brent-Luk.
// Carried squared norms (Rutishauser), DPP row_shr/row_shl migration.
__global__ __launch_bounds__(256) void k_svd(const float* __restrict__ Q,
                                             const float* __restrict__ K,
                                             const float* __restrict__ T,
                                             const float* __restrict__ detT,
                                             float* __restrict__ Sign) {
  int gtid = blockIdx.x * 256 + threadIdx.x;
  int gid = gtid >> 3;          // matrix id, < 131072
  int l = gtid & 7;
  int k = gid & 15, m = (gid >> 4) & 63, n = (gid >> 10) & 63, b = gid >> 16;
  const float* qrow = Q + (b * 64 + n) * 16;
  const float* krow = K + (b * 64 + m) * 16;

  float qv[16];
#pragma unroll
  for (int i = 0; i < 16; ++i) qv[i] = qrow[i];

  float trace = 0.f, pq = 1.f, pk = 1.f;
#pragma unroll
  for (int i = 0; i < 16; ++i) {
    float kv = krow[i];
    pq *= qv[i]; pk *= kv;
    trace += qv[i] * kv * T[i * 272 + k];   // T[i,i,k]
  }
  float det = pq * pk * detT[k];

  float t0[16], b0[16];
  {
    int jt = 2 * l, jb = 2 * l + 1;
    float kt = krow[jt], kb = krow[jb];
#pragma unroll
    for (int i = 0; i < 16; ++i) {
      t0[i] = qv[i] * T[i * 256 + jt * 16 + k] * kt;
      b0[i] = qv[i] * T[i * 256 + jb * 16 + k] * kb;
    }
  }

  // initial squared column norms (carried exactly through rotations)
  float al = 0.f, be = 0.f;
#pragma unroll
  for (int i = 0; i < 16; ++i) {
    al = fmaf(t0[i], t0[i], al);
    be = fmaf(b0[i], b0[i], be);
  }

  bool l0 = (l == 0), l7 = (l == 7);

  for (int round = 0; round < SWEEPS * 15; ++round) {
    float ga = 0.f;
#pragma unroll
    for (int i = 0; i < 16; ++i) ga = fmaf(t0[i], b0[i], ga);
    float zeta = __fdividef(be - al, 2.0f * ga);
    float tt = __fdividef(copysignf(1.0f, zeta),
                          fabsf(zeta) + sqrtf(fmaf(zeta, zeta, 1.0f)));
    tt = (ga == 0.0f) ? 0.0f : tt;   // kill NaN from 0/0
    float c = rsqrtf(fmaf(tt, tt, 1.0f));
    float s = c * tt, ns = -s;
#pragma unroll
    for (int i = 0; i < 16; ++i) {
      float ti = t0[i], bi = b0[i];
      t0[i] = fmaf(ns, bi, c * ti);
      b0[i] = fmaf(s, ti, c * bi);
    }
    float tg = tt * ga;
    al -= tg; be += tg;              // Rutishauser norm update (exact)

    // Brent-Luk migration: top shifts right (recv lane-1), bottom shifts left
    // (recv lane+1); l0 keeps its top, l7's bottom takes its old top.
#pragma unroll
    for (int i = 0; i < 16; ++i) {
      float st = l0 ? b0[i] : t0[i];     // what lane l sends to (l+1)'s top
      float r1 = dppf<0x111>(st);        // from lane-1
      float r2 = dppf<0x101>(b0[i]);     // from lane+1
      float ot = t0[i];
      t0[i] = l0 ? ot : r1;
      b0[i] = l7 ? ot : r2;
    }
    {  // migrate the carried norms alongside their columns
      float sa = l0 ? be : al;
      float r1 = dppf<0x111>(sa);
      float r2 = dppf<0x101>(be);
      float oa = al;
      al = l0 ? oa : r1;
      be = l7 ? oa : r2;
    }
  }

  // exact final norms
  float nt2 = 0.f, nb2 = 0.f;
#pragma unroll
  for (int i = 0; i < 16; ++i) {
    nt2 = fmaf(t0[i], t0[i], nt2);
    nb2 = fmaf(b0[i], b0[i], nb2);
  }
  float nu = sqrtf(nt2), nv = sqrtf(nb2);
  float lmin = fminf(nu, nv), lmax = fmaxf(nu, nv);
  float lsum = logf(nu + EPSF) + logf(nv + EPSF);
#pragma unroll
  for (int off = 1; off < 8; off <<= 1) {
    lmin = fminf(lmin, __shfl_xor(lmin, off, 64));
    lmax = fmaxf(lmax, __shfl_xor(lmax, off, 64));
    lsum += __shfl_xor(lsum, off, 64);
  }
  if (l == 0) {
    float* sp = Sign + (((b * 64 + n) * 64 + m) * 6) * 16 + k;
    sp[0]  = det;
    sp[16] = trace;
    sp[32] = lsum;
    sp[48] = lmin;
    sp[64] = lmax;
  }
}

// ---------------- rho: repeated squaring, quad_perm broadcast, no LDS ----------------
// 4 lanes/matrix (one quad). Column kk lives in lane kk>>2, slot kk&3.
// quad_perm broadcast of the owner lane's slot gives every lane column kk.
template <int SRCL>
__device__ __forceinline__ void rho_quarter(float (&a)[4][16], float (&acc)[4][16]) {
  constexpr int CTRL = SRCL | (SRCL << 2) | (SRCL << 4) | (SRCL << 6);  // quad bcast
#pragma unroll
  for (int c = 0; c < 4; ++c) {        // global column kk = SRCL*4 + c
    float colk[16];
#pragma unroll
    for (int i = 0; i < 16; ++i) colk[i] = dppf<CTRL>(a[c][i]);  // A[i][kk]
#pragma unroll
    for (int jj = 0; jj < 4; ++jj) {
      float f = a[jj][SRCL * 4 + c];   // A[kk][own col jj] (static index)
#pragma unroll
      for (int i = 0; i < 16; ++i) acc[jj][i] = fmaf(colk[i], f, acc[jj][i]);
    }
  }
}

__global__ __launch_bounds__(128) void k_rho(const float* __restrict__ Q,
                                             const float* __restrict__ K,
                                             const float* __restrict__ T,
                                             float* __restrict__ Sign) {
  int gtid = blockIdx.x * 128 + threadIdx.x;
  int gid = gtid >> 2;              // matrix id, < 131072
  int l = threadIdx.x & 3;
  int k = gid & 15, m = (gid >> 4) & 63, n = (gid >> 10) & 63, b = gid >> 16;
  const float* qrow = Q + (b * 64 + n) * 16;
  const float* krow = K + (b * 64 + m) * 16;

  float a[4][16];
#pragma unroll
  for (int jj = 0; jj < 4; ++jj) {
    int j = 4 * l + jj;
    float w = qrow[j] * krow[j];
#pragma unroll
    for (int i = 0; i < 16; ++i) a[jj][i] = T[i * 256 + j * 16 + k] * w;
  }

  float L = 0.0f, wgt = 0.5f;
  for (int it = 0; it <= RHO_J; ++it) {
    float ss = 0.f;
#pragma unroll
    for (int jj = 0; jj < 4; ++jj)
#pragma unroll
      for (int i = 0; i < 16; ++i) ss = fmaf(a[jj][i], a[jj][i], ss);
    ss += __shfl_xor(ss, 1, 64);
    ss += __shfl_xor(ss, 2, 64);
    L += logf(ss) * wgt;
    wgt *= 0.5f;
    if (it == RHO_J) break;
    float s = (ss > 0.0f) ? (1.0f / ss) : 0.0f;

    float acc[4][16];
#pragma unroll
    for (int jj = 0; jj < 4; ++jj)
#pragma unroll
      for (int i = 0; i < 16; ++i) acc[jj][i] = 0.f;

    rho_quarter<0>(a, acc);
    rho_quarter<1>(a, acc);
    rho_quarter<2>(a, acc);
    rho_quarter<3>(a, acc);

#pragma unroll
    for (int jj = 0; jj < 4; ++jj)
#pragma unroll
      for (int i = 0; i < 16; ++i) a[jj][i] = acc[jj][i] * s;
  }
  float rho = expf(L);
  if (l == 0) Sign[(((b * 64 + n) * 64 + m) * 6 + 5) * 16 + k] = rho;
}

// ---------------- out[b,n,v] = sum_{m,s,k} Sign * V ----------------
__global__ __launch_bounds__(256) void k_out(const float* __restrict__ Sign,
                                             const float* __restrict__ V,
                                             float* __restrict__ out) {
  __shared__ float red[256];
  int bn = blockIdx.x;              // 0..127
  int b = bn >> 6;
  int t = threadIdx.x;
  int v = t & 15, mc = t >> 4;      // m in [mc*4, mc*4+4)
  const float* sp = Sign + bn * 6144;
  const float* vp = V + b * 98304;
  float acc = 0.f;
  for (int mm = 0; mm < 4; ++mm) {
    int m = mc * 4 + mm;
    const float* sr = sp + m * 96;
    const float* vr = vp + m * 1536 + v;
#pragma unroll
    for (int sk = 0; sk < 96; ++sk) acc = fmaf(sr[sk], vr[sk * 16], acc);
  }
  red[t] = acc;
  __syncthreads();
  for (int off = 128; off >= 16; off >>= 1) {
    if (t < off) red[t] += red[t + off];
    __syncthreads();
  }
  if (t < 16) out[bn * 16 + t] = red[t];
}

extern "C" void kernel_launch(void* const* d_in, const int* in_sizes, int n_in,
                              void* d_out, int out_size, void* d_ws, size_t ws_size,
                              hipStream_t stream) {
  const float* X  = (const float*)d_in[0];
  const float* Wk = (const float*)d_in[1];
  const float* Wq = (const float*)d_in[2];
  const float* T  = (const float*)d_in[3];
  const float* Wv = (const float*)d_in[4];
  float* out = (float*)d_out;
  float* ws = (float*)d_ws;

  float* Q    = ws + WS_Q;
  float* K    = ws + WS_K;
  float* detT = ws + WS_DETT;
  float* V    = ws + WS_V;
  float* Sign = ws + WS_SIGN;

  hipLaunchKernelGGL(k_qk,   dim3(8),    dim3(256), 0, stream, X, Wk, Wq, Q, K);
  hipLaunchKernelGGL(k_dett, dim3(1),    dim3(64),  0, stream, T, detT);
  hipLaunchKernelGGL(k_v,    dim3(768),  dim3(256), 0, stream, X, Wv, V);
  hipLaunchKernelGGL(k_svd,  dim3(4096), dim3(256), 0, stream, Q, K, T, detT, Sign);
  hipLaunchKernelGGL(k_rho,  dim3(4096), dim3(128), 0, stream, Q, K, T, Sign);
  hipLaunchKernelGGL(k_out,  dim3(128),  dim3(256), 0, stream, Sign, V, out);
}

// Round 5
// 693.634 us; speedup vs baseline: 2.1502x; 1.1284x over previous
//
#include <hip/hip_runtime.h>
#include <math.h>

// Problem: B=2, N=64, D=16.
// C_{b,n,m,k} = diag(Q_n) T_k diag(K_m), 131072 16x16 matrices.
// det/trace closed-form; sigma via one-sided block-Jacobi (4 lanes x 4 cols,
// GF(4) spread schedule, all comm = quad_perm DPP); rho via normalized
// repeated squaring with quad_perm broadcast (no LDS, no barriers).

#define EPSF 1e-6f
#define SWEEPS 6
#define RHO_J 12

// workspace float offsets
#define WS_Q    0         // [2][64][16]            = 2048
#define WS_K    2048      // [2][64][16]            = 2048
#define WS_DETT 4096      // [16]
#define WS_V    4352      // [2][64][6][16][16]     = 196608
#define WS_SIGN 200960    // [2][64][64][6][16]     = 786432

// quad_perm DPP: ctrl = p0|p1<<2|p2<<4|p3<<6; XOR masks: 1->0xB1, 2->0x4E, 3->0x1B
template <int CTRL>
__device__ __forceinline__ float dppf(float v) {
  return __int_as_float(__builtin_amdgcn_update_dpp(
      0, __float_as_int(v), CTRL, 0xF, 0xF, true));
}

// ---------------- Q = X Wq, K = X Wk ----------------
__global__ __launch_bounds__(256) void k_qk(const float* __restrict__ X,
                                            const float* __restrict__ Wk,
                                            const float* __restrict__ Wq,
                                            float* __restrict__ Q,
                                            float* __restrict__ Kout) {
  int t = blockIdx.x * 256 + threadIdx.x;   // exactly 2048 threads
  int i = t & 15, bn = t >> 4;
  const float* x = X + bn * 16;
  float q = 0.f, kk = 0.f;
#pragma unroll
  for (int d = 0; d < 16; ++d) {
    float xv = x[d];
    q  += xv * Wq[d * 16 + i];
    kk += xv * Wk[d * 16 + i];
  }
  Q[t] = q; Kout[t] = kk;
}

// ---------------- det(T_k) via LU with partial pivoting ----------------
__global__ __launch_bounds__(64) void k_dett(const float* __restrict__ T,
                                             float* __restrict__ detT) {
  __shared__ float A[16][16][16];  // [k][i][j]
  for (int idx = threadIdx.x; idx < 4096; idx += 64) {
    int i = idx >> 8, j = (idx >> 4) & 15, kk = idx & 15;
    A[kk][i][j] = T[idx];          // T[i,j,k] at i*256+j*16+k
  }
  __syncthreads();
  int k = threadIdx.x;
  if (k < 16) {
    float det = 1.0f;
    for (int c = 0; c < 16; ++c) {
      int p = c; float mx = fabsf(A[k][c][c]);
      for (int r = c + 1; r < 16; ++r) {
        float v = fabsf(A[k][r][c]);
        if (v > mx) { mx = v; p = r; }
      }
      if (mx == 0.0f) { det = 0.0f; break; }
      if (p != c) {
        det = -det;
        for (int cc = c; cc < 16; ++cc) {
          float tmp = A[k][c][cc]; A[k][c][cc] = A[k][p][cc]; A[k][p][cc] = tmp;
        }
      }
      float piv = A[k][c][c];
      det *= piv;
      float inv = 1.0f / piv;
      for (int r = c + 1; r < 16; ++r) {
        float f = A[k][r][c] * inv;
        for (int cc = c + 1; cc < 16; ++cc) A[k][r][cc] -= f * A[k][c][cc];
      }
    }
    detT[k] = det;
  }
}

// ---------------- V = einsum('bmd,dskv->bmskv') ----------------
__global__ __launch_bounds__(256) void k_v(const float* __restrict__ X,
                                           const float* __restrict__ Wv,
                                           float* __restrict__ V) {
  int t = blockIdx.x * 256 + threadIdx.x;   // exactly 196608 threads
  int bm = t / 1536; int rem = t - bm * 1536;
  int s = rem >> 8; int kk = (rem >> 4) & 15; int v = rem & 15;
  const float* x = X + bm * 16;
  float acc = 0.f;
#pragma unroll
  for (int d = 0; d < 16; ++d) acc += x[d] * Wv[((d * 6 + s) * 16 + kk) * 16 + v];
  V[t] = acc;
}

// ---------------- Jacobi helpers ----------------
__device__ __forceinline__ void rot_coeff(float al, float be, float ga,
                                          float& cc, float& ss, float& tg) {
  float zeta = __fdividef(be - al, 2.0f * ga);
  float tt = __fdividef(copysignf(1.0f, zeta),
                        fabsf(zeta) + sqrtf(fmaf(zeta, zeta, 1.0f)));
  tt = (ga == 0.0f) ? 0.0f : tt;   // kill NaN from 0/0
  cc = rsqrtf(fmaf(tt, tt, 1.0f));
  ss = cc * tt;
  tg = tt * ga;
}

// lane-local rotation of columns a (top) / b (bottom) with carried norms
__device__ __forceinline__ void rot2(float (&a)[16], float (&b)[16],
                                     float& na, float& nb) {
  float ga = 0.f;
#pragma unroll
  for (int i = 0; i < 16; ++i) ga = fmaf(a[i], b[i], ga);
  float cc, ss, tg; rot_coeff(na, nb, ga, cc, ss, tg);
  float ns = -ss;
#pragma unroll
  for (int i = 0; i < 16; ++i) {
    float ti = a[i], bi = b[i];
    a[i] = fmaf(ns, bi, cc * ti);
    b[i] = fmaf(ss, ti, cc * bi);
  }
  na -= tg; nb += tg;
}

// cross-lane rotation: pair = (own col, partner-lane col at same slot).
// Both lanes compute bit-identical coefficients; role picks top/bottom.
template <int CTRL>
__device__ __forceinline__ void xrot(float (&a)[16], float& na, bool top) {
  float oth[16];
#pragma unroll
  for (int i = 0; i < 16; ++i) oth[i] = dppf<CTRL>(a[i]);
  float on = dppf<CTRL>(na);
  float al = top ? na : on, be = top ? on : na;
  float ga = 0.f;
#pragma unroll
  for (int i = 0; i < 16; ++i) ga = fmaf(a[i], oth[i], ga);
  float cc, ss, tg; rot_coeff(al, be, ga, cc, ss, tg);
  float s2 = top ? -ss : ss;
#pragma unroll
  for (int i = 0; i < 16; ++i) a[i] = fmaf(s2, oth[i], cc * a[i]);
  na += top ? -tg : tg;
}

// config-transition move of one slot's column+norm (XOR within quad)
template <int CTRL>
__device__ __forceinline__ void tmov(float (&a)[16], float& na) {
#pragma unroll
  for (int i = 0; i < 16; ++i) a[i] = dppf<CTRL>(a[i]);
  na = dppf<CTRL>(na);
}

// ---------------- SVD features + det + trace ----------------
// 4 lanes/matrix (one quad), 4 cols/lane. Schedule per sweep (120 pairs, each
// exactly once): 3 cross-XOR phases (same-x pairs, 24) + 4 slope configs
// (group = y XOR slope*x over GF(4), slot = x) with 6 local rotations each (96).
// Transitions between slope configs are XOR quad_perms (slot preserved).
__global__ __launch_bounds__(256) void k_svd(const float* __restrict__ Q,
                                             const float* __restrict__ K,
                                             const float* __restrict__ T,
                                             const float* __restrict__ detT,
                                             float* __restrict__ Sign) {
  int gtid = blockIdx.x * 256 + threadIdx.x;
  int gid = gtid >> 2;          // matrix id, < 131072
  int l = threadIdx.x & 3;      // quad lane = group id
  int k = gid & 15, m = (gid >> 4) & 63, n = (gid >> 10) & 63, b = gid >> 16;
  const float* qrow = Q + (b * 64 + n) * 16;
  const float* krow = K + (b * 64 + m) * 16;

  float qv[16];
#pragma unroll
  for (int i = 0; i < 16; ++i) qv[i] = qrow[i];

  float trace = 0.f, pq = 1.f, pk = 1.f;
#pragma unroll
  for (int i = 0; i < 16; ++i) {
    float kv = krow[i];
    pq *= qv[i]; pk *= kv;
    trace += qv[i] * kv * T[i * 272 + k];   // T[i,i,k]
  }
  float det = pq * pk * detT[k];

  // init in slope-0 config: slot s holds col (x=s, y=l), col index 4s+l
  float c0[16], c1[16], c2[16], c3[16];
  float nn0, nn1, nn2, nn3;
  {
    int j0 = l, j1 = 4 + l, j2 = 8 + l, j3 = 12 + l;
    float k0 = krow[j0], k1 = krow[j1], k2 = krow[j2], k3 = krow[j3];
#pragma unroll
    for (int i = 0; i < 16; ++i) {
      float qi = qv[i];
      c0[i] = qi * T[i * 256 + j0 * 16 + k] * k0;
      c1[i] = qi * T[i * 256 + j1 * 16 + k] * k1;
      c2[i] = qi * T[i * 256 + j2 * 16 + k] * k2;
      c3[i] = qi * T[i * 256 + j3 * 16 + k] * k3;
    }
    nn0 = nn1 = nn2 = nn3 = 0.f;
#pragma unroll
    for (int i = 0; i < 16; ++i) {
      nn0 = fmaf(c0[i], c0[i], nn0);
      nn1 = fmaf(c1[i], c1[i], nn1);
      nn2 = fmaf(c2[i], c2[i], nn2);
      nn3 = fmaf(c3[i], c3[i], nn3);
    }
  }

  bool r1 = (l & 1) == 0;   // top role for delta=1 (pairs 0-1, 2-3)
  bool r2 = (l & 2) == 0;   // top role for delta=2 and delta=3

#define INTRA6() { rot2(c0,c1,nn0,nn1); rot2(c2,c3,nn2,nn3); \
                   rot2(c0,c2,nn0,nn2); rot2(c1,c3,nn1,nn3); \
                   rot2(c0,c3,nn0,nn3); rot2(c1,c2,nn1,nn2); }

  for (int sw = 0; sw < SWEEPS; ++sw) {
    // cross-lane phases (same-x pairs), done in slope-0 layout
    xrot<0xB1>(c0, nn0, r1); xrot<0xB1>(c1, nn1, r1);
    xrot<0xB1>(c2, nn2, r1); xrot<0xB1>(c3, nn3, r1);
    xrot<0x4E>(c0, nn0, r2); xrot<0x4E>(c1, nn1, r2);
    xrot<0x4E>(c2, nn2, r2); xrot<0x4E>(c3, nn3, r2);
    xrot<0x1B>(c0, nn0, r2); xrot<0x1B>(c1, nn1, r2);
    xrot<0x1B>(c2, nn2, r2); xrot<0x1B>(c3, nn3, r2);

    INTRA6();                                   // slope 0
    // slope0 -> slope1 (delta=1): slot s moves by XOR mul(1,s)=s
    tmov<0xB1>(c1, nn1); tmov<0x4E>(c2, nn2); tmov<0x1B>(c3, nn3);
    INTRA6();                                   // slope 1
    // slope1 -> slope2 (delta=3): slot s moves by XOR mul(3,s) = 3,1,2
    tmov<0x1B>(c1, nn1); tmov<0xB1>(c2, nn2); tmov<0x4E>(c3, nn3);
    INTRA6();                                   // slope 2
    // slope2 -> slope3 (delta=1)
    tmov<0xB1>(c1, nn1); tmov<0x4E>(c2, nn2); tmov<0x1B>(c3, nn3);
    INTRA6();                                   // slope 3
    // slope3 -> slope0 (delta=3)
    tmov<0x1B>(c1, nn1); tmov<0xB1>(c2, nn2); tmov<0x4E>(c3, nn3);
  }
#undef INTRA6

  // exact final norms (4 per lane), reduce across the quad
  float n2_0 = 0.f, n2_1 = 0.f, n2_2 = 0.f, n2_3 = 0.f;
#pragma unroll
  for (int i = 0; i < 16; ++i) {
    n2_0 = fmaf(c0[i], c0[i], n2_0);
    n2_1 = fmaf(c1[i], c1[i], n2_1);
    n2_2 = fmaf(c2[i], c2[i], n2_2);
    n2_3 = fmaf(c3[i], c3[i], n2_3);
  }
  float s0 = sqrtf(n2_0), s1 = sqrtf(n2_1), s2 = sqrtf(n2_2), s3 = sqrtf(n2_3);
  float lmin = fminf(fminf(s0, s1), fminf(s2, s3));
  float lmax = fmaxf(fmaxf(s0, s1), fmaxf(s2, s3));
  float lsum = logf(s0 + EPSF) + logf(s1 + EPSF) + logf(s2 + EPSF) + logf(s3 + EPSF);
#pragma unroll
  for (int off = 1; off < 4; off <<= 1) {
    lmin = fminf(lmin, __shfl_xor(lmin, off, 64));
    lmax = fmaxf(lmax, __shfl_xor(lmax, off, 64));
    lsum += __shfl_xor(lsum, off, 64);
  }
  if (l == 0) {
    float* sp = Sign + (((b * 64 + n) * 64 + m) * 6) * 16 + k;
    sp[0]  = det;
    sp[16] = trace;
    sp[32] = lsum;
    sp[48] = lmin;
    sp[64] = lmax;
  }
}

// ---------------- rho: repeated squaring, quad_perm broadcast, no LDS ----------------
template <int SRCL>
__device__ __forceinline__ void rho_quarter(float (&a)[4][16], float (&acc)[4][16]) {
  constexpr int CTRL = SRCL | (SRCL << 2) | (SRCL << 4) | (SRCL << 6);  // quad bcast
#pragma unroll
  for (int c = 0; c < 4; ++c) {        // global column kk = SRCL*4 + c
    float colk[16];
#pragma unroll
    for (int i = 0; i < 16; ++i) colk[i] = dppf<CTRL>(a[c][i]);  // A[i][kk]
#pragma unroll
    for (int jj = 0; jj < 4; ++jj) {
      float f = a[jj][SRCL * 4 + c];   // A[kk][own col jj] (static index)
#pragma unroll
      for (int i = 0; i < 16; ++i) acc[jj][i] = fmaf(colk[i], f, acc[jj][i]);
    }
  }
}

__global__ __launch_bounds__(128) void k_rho(const float* __restrict__ Q,
                                             const float* __restrict__ K,
                                             const float* __restrict__ T,
                                             float* __restrict__ Sign) {
  int gtid = blockIdx.x * 128 + threadIdx.x;
  int gid = gtid >> 2;              // matrix id, < 131072
  int l = threadIdx.x & 3;
  int k = gid & 15, m = (gid >> 4) & 63, n = (gid >> 10) & 63, b = gid >> 16;
  const float* qrow = Q + (b * 64 + n) * 16;
  const float* krow = K + (b * 64 + m) * 16;

  float a[4][16];
#pragma unroll
  for (int jj = 0; jj < 4; ++jj) {
    int j = 4 * l + jj;
    float w = qrow[j] * krow[j];
#pragma unroll
    for (int i = 0; i < 16; ++i) a[jj][i] = T[i * 256 + j * 16 + k] * w;
  }

  float L = 0.0f, wgt = 0.5f;
  for (int it = 0; it <= RHO_J; ++it) {
    float ss = 0.f;
#pragma unroll
    for (int jj = 0; jj < 4; ++jj)
#pragma unroll
      for (int i = 0; i < 16; ++i) ss = fmaf(a[jj][i], a[jj][i], ss);
    ss += __shfl_xor(ss, 1, 64);
    ss += __shfl_xor(ss, 2, 64);
    L += logf(ss) * wgt;
    wgt *= 0.5f;
    if (it == RHO_J) break;
    float s = (ss > 0.0f) ? (1.0f / ss) : 0.0f;

    float acc[4][16];
#pragma unroll
    for (int jj = 0; jj < 4; ++jj)
#pragma unroll
      for (int i = 0; i < 16; ++i) acc[jj][i] = 0.f;

    rho_quarter<0>(a, acc);
    rho_quarter<1>(a, acc);
    rho_quarter<2>(a, acc);
    rho_quarter<3>(a, acc);

#pragma unroll
    for (int jj = 0; jj < 4; ++jj)
#pragma unroll
      for (int i = 0; i < 16; ++i) a[jj][i] = acc[jj][i] * s;
  }
  float rho = expf(L);
  if (l == 0) Sign[(((b * 64 + n) * 64 + m) * 6 + 5) * 16 + k] = rho;
}

// ---------------- out[b,n,v] = sum_{m,s,k} Sign * V ----------------
__global__ __launch_bounds__(256) void k_out(const float* __restrict__ Sign,
                                             const float* __restrict__ V,
                                             float* __restrict__ out) {
  __shared__ float red[256];
  int bn = blockIdx.x;              // 0..127
  int b = bn >> 6;
  int t = threadIdx.x;
  int v = t & 15, mc = t >> 4;      // m in [mc*4, mc*4+4)
  const float* sp = Sign + bn * 6144;
  const float* vp = V + b * 98304;
  float acc = 0.f;
  for (int mm = 0; mm < 4; ++mm) {
    int m = mc * 4 + mm;
    const float* sr = sp + m * 96;
    const float* vr = vp + m * 1536 + v;
#pragma unroll
    for (int sk = 0; sk < 96; ++sk) acc = fmaf(sr[sk], vr[sk * 16], acc);
  }
  red[t] = acc;
  __syncthreads();
  for (int off = 128; off >= 16; off >>= 1) {
    if (t < off) red[t] += red[t + off];
    __syncthreads();
  }
  if (t < 16) out[bn * 16 + t] = red[t];
}

extern "C" void kernel_launch(void* const* d_in, const int* in_sizes, int n_in,
                              void* d_out, int out_size, void* d_ws, size_t ws_size,
                              hipStream_t stream) {
  const float* X  = (const float*)d_in[0];
  const float* Wk = (const float*)d_in[1];
  const float* Wq = (const float*)d_in[2];
  const float* T  = (const float*)d_in[3];
  const float* Wv = (const float*)d_in[4];
  float* out = (float*)d_out;
  float* ws = (float*)d_ws;

  float* Q    = ws + WS_Q;
  float* K    = ws + WS_K;
  float* detT = ws + WS_DETT;
  float* V    = ws + WS_V;
  float* Sign = ws + WS_SIGN;

  hipLaunchKernelGGL(k_qk,   dim3(8),    dim3(256), 0, stream, X, Wk, Wq, Q, K);
  hipLaunchKernelGGL(k_dett, dim3(1),    dim3(64),  0, stream, T, detT);
  hipLaunchKernelGGL(k_v,    dim3(768),  dim3(256), 0, stream, X, Wv, V);
  hipLaunchKernelGGL(k_svd,  dim3(2048), dim3(256), 0, stream, Q, K, T, detT, Sign);
  hipLaunchKernelGGL(k_rho,  dim3(4096), dim3(128), 0, stream, Q, K, T, Sign);
  hipLaunchKernelGGL(k_out,  dim3(128),  dim3(256), 0, stream, Sign, V, out);
}

// Round 6
// 573.234 us; speedup vs baseline: 2.6018x; 1.2100x over previous
//
#include <hip/hip_runtime.h>
#include <math.h>

// Problem: B=2, N=64, D=16.
// C_{b,n,m,k} = diag(Q_n) T_k diag(K_m), 131072 16x16 matrices.
// det/trace closed-form; sigma via one-sided block-Jacobi (4 lanes x 4 cols,
// GF(4) spread schedule, all comm = 1-inst mov_dpp); rho via normalized
// repeated squaring with quad_perm broadcast (no LDS, no barriers).
// R6: raw HW transcendentals (v_sqrt/v_rcp/v_rsq/v_log/v_exp), mov_dpp,
// split accumulator chains.

#define EPSF 1e-6f
#define SWEEPS 6
#define RHO_J 12

// workspace float offsets
#define WS_Q    0         // [2][64][16]            = 2048
#define WS_K    2048      // [2][64][16]            = 2048
#define WS_DETT 4096      // [16]
#define WS_V    4352      // [2][64][6][16][16]     = 196608
#define WS_SIGN 200960    // [2][64][64][6][16]     = 786432

// quad_perm DPP: ctrl = p0|p1<<2|p2<<4|p3<<6; XOR masks: 1->0xB1, 2->0x4E, 3->0x1B
template <int CTRL>
__device__ __forceinline__ float dppf(float v) {
  return __int_as_float(__builtin_amdgcn_mov_dpp(__float_as_int(v), CTRL, 0xF, 0xF, true));
}
__device__ __forceinline__ float fsqrt_fast(float x) { return __builtin_amdgcn_sqrtf(x); }
__device__ __forceinline__ float frcp_fast(float x)  { return __builtin_amdgcn_rcpf(x); }
__device__ __forceinline__ float frsq_fast(float x)  { return __builtin_amdgcn_rsqf(x); }

// ---------------- Q = X Wq, K = X Wk ----------------
__global__ __launch_bounds__(256) void k_qk(const float* __restrict__ X,
                                            const float* __restrict__ Wk,
                                            const float* __restrict__ Wq,
                                            float* __restrict__ Q,
                                            float* __restrict__ Kout) {
  int t = blockIdx.x * 256 + threadIdx.x;   // exactly 2048 threads
  int i = t & 15, bn = t >> 4;
  const float* x = X + bn * 16;
  float q = 0.f, kk = 0.f;
#pragma unroll
  for (int d = 0; d < 16; ++d) {
    float xv = x[d];
    q  += xv * Wq[d * 16 + i];
    kk += xv * Wk[d * 16 + i];
  }
  Q[t] = q; Kout[t] = kk;
}

// ---------------- det(T_k) via LU with partial pivoting ----------------
__global__ __launch_bounds__(64) void k_dett(const float* __restrict__ T,
                                             float* __restrict__ detT) {
  __shared__ float A[16][16][16];  // [k][i][j]
  for (int idx = threadIdx.x; idx < 4096; idx += 64) {
    int i = idx >> 8, j = (idx >> 4) & 15, kk = idx & 15;
    A[kk][i][j] = T[idx];          // T[i,j,k] at i*256+j*16+k
  }
  __syncthreads();
  int k = threadIdx.x;
  if (k < 16) {
    float det = 1.0f;
    for (int c = 0; c < 16; ++c) {
      int p = c; float mx = fabsf(A[k][c][c]);
      for (int r = c + 1; r < 16; ++r) {
        float v = fabsf(A[k][r][c]);
        if (v > mx) { mx = v; p = r; }
      }
      if (mx == 0.0f) { det = 0.0f; break; }
      if (p != c) {
        det = -det;
        for (int cc = c; cc < 16; ++cc) {
          float tmp = A[k][c][cc]; A[k][c][cc] = A[k][p][cc]; A[k][p][cc] = tmp;
        }
      }
      float piv = A[k][c][c];
      det *= piv;
      float inv = 1.0f / piv;
      for (int r = c + 1; r < 16; ++r) {
        float f = A[k][r][c] * inv;
        for (int cc = c + 1; cc < 16; ++cc) A[k][r][cc] -= f * A[k][c][cc];
      }
    }
    detT[k] = det;
  }
}

// ---------------- V = einsum('bmd,dskv->bmskv') ----------------
__global__ __launch_bounds__(256) void k_v(const float* __restrict__ X,
                                           const float* __restrict__ Wv,
                                           float* __restrict__ V) {
  int t = blockIdx.x * 256 + threadIdx.x;   // exactly 196608 threads
  int bm = t / 1536; int rem = t - bm * 1536;
  int s = rem >> 8; int kk = (rem >> 4) & 15; int v = rem & 15;
  const float* x = X + bm * 16;
  float acc = 0.f;
#pragma unroll
  for (int d = 0; d < 16; ++d) acc += x[d] * Wv[((d * 6 + s) * 16 + kk) * 16 + v];
  V[t] = acc;
}

// ---------------- Jacobi helpers ----------------
__device__ __forceinline__ void rot_coeff(float al, float be, float ga,
                                          float& cc, float& ss, float& tg) {
  float zeta = (be - al) * frcp_fast(ga + ga);
  float tt = copysignf(frcp_fast(fabsf(zeta) + fsqrt_fast(fmaf(zeta, zeta, 1.0f))),
                       zeta);
  tt = (ga == 0.0f) ? 0.0f : tt;   // kill NaN from 0/0
  cc = frsq_fast(fmaf(tt, tt, 1.0f));
  ss = cc * tt;
  tg = tt * ga;
}

// lane-local rotation of columns a (top) / b (bottom) with carried norms
__device__ __forceinline__ void rot2(float (&a)[16], float (&b)[16],
                                     float& na, float& nb) {
  float g0 = 0.f, g1 = 0.f;
#pragma unroll
  for (int i = 0; i < 8; ++i) {
    g0 = fmaf(a[i], b[i], g0);
    g1 = fmaf(a[i + 8], b[i + 8], g1);
  }
  float ga = g0 + g1;
  float cc, ss, tg; rot_coeff(na, nb, ga, cc, ss, tg);
  float ns = -ss;
#pragma unroll
  for (int i = 0; i < 16; ++i) {
    float ti = a[i], bi = b[i];
    a[i] = fmaf(ns, bi, cc * ti);
    b[i] = fmaf(ss, ti, cc * bi);
  }
  na -= tg; nb += tg;
}

// cross-lane rotation: pair = (own col, partner-lane col at same slot).
// Both lanes compute bit-identical coefficients; role picks top/bottom.
template <int CTRL>
__device__ __forceinline__ void xrot(float (&a)[16], float& na, bool top) {
  float oth[16];
#pragma unroll
  for (int i = 0; i < 16; ++i) oth[i] = dppf<CTRL>(a[i]);
  float on = dppf<CTRL>(na);
  float al = top ? na : on, be = top ? on : na;
  float g0 = 0.f, g1 = 0.f;
#pragma unroll
  for (int i = 0; i < 8; ++i) {
    g0 = fmaf(a[i], oth[i], g0);
    g1 = fmaf(a[i + 8], oth[i + 8], g1);
  }
  float ga = g0 + g1;
  float cc, ss, tg; rot_coeff(al, be, ga, cc, ss, tg);
  float s2 = top ? -ss : ss;
#pragma unroll
  for (int i = 0; i < 16; ++i) a[i] = fmaf(s2, oth[i], cc * a[i]);
  na += top ? -tg : tg;
}

// config-transition move of one slot's column+norm (XOR within quad)
template <int CTRL>
__device__ __forceinline__ void tmov(float (&a)[16], float& na) {
#pragma unroll
  for (int i = 0; i < 16; ++i) a[i] = dppf<CTRL>(a[i]);
  na = dppf<CTRL>(na);
}

// ---------------- SVD features + det + trace ----------------
// 4 lanes/matrix (one quad), 4 cols/lane. Schedule per sweep (120 pairs, each
// exactly once): 3 cross-XOR phases (same-x pairs, 24) + 4 slope configs
// (group = y XOR slope*x over GF(4), slot = x) with 6 local rotations each (96).
// Transitions between slope configs are XOR quad_perms (slot preserved).
__global__ __launch_bounds__(256) void k_svd(const float* __restrict__ Q,
                                             const float* __restrict__ K,
                                             const float* __restrict__ T,
                                             const float* __restrict__ detT,
                                             float* __restrict__ Sign) {
  int gtid = blockIdx.x * 256 + threadIdx.x;
  int gid = gtid >> 2;          // matrix id, < 131072
  int l = threadIdx.x & 3;      // quad lane = group id
  int k = gid & 15, m = (gid >> 4) & 63, n = (gid >> 10) & 63, b = gid >> 16;
  const float* qrow = Q + (b * 64 + n) * 16;
  const float* krow = K + (b * 64 + m) * 16;

  float qv[16];
#pragma unroll
  for (int i = 0; i < 16; ++i) qv[i] = qrow[i];

  float trace = 0.f, pq = 1.f, pk = 1.f;
#pragma unroll
  for (int i = 0; i < 16; ++i) {
    float kv = krow[i];
    pq *= qv[i]; pk *= kv;
    trace += qv[i] * kv * T[i * 272 + k];   // T[i,i,k]
  }
  float det = pq * pk * detT[k];

  // init in slope-0 config: slot s holds col (x=s, y=l), col index 4s+l
  float c0[16], c1[16], c2[16], c3[16];
  float nn0, nn1, nn2, nn3;
  {
    int j0 = l, j1 = 4 + l, j2 = 8 + l, j3 = 12 + l;
    float k0 = krow[j0], k1 = krow[j1], k2 = krow[j2], k3 = krow[j3];
#pragma unroll
    for (int i = 0; i < 16; ++i) {
      float qi = qv[i];
      c0[i] = qi * T[i * 256 + j0 * 16 + k] * k0;
      c1[i] = qi * T[i * 256 + j1 * 16 + k] * k1;
      c2[i] = qi * T[i * 256 + j2 * 16 + k] * k2;
      c3[i] = qi * T[i * 256 + j3 * 16 + k] * k3;
    }
    nn0 = nn1 = nn2 = nn3 = 0.f;
#pragma unroll
    for (int i = 0; i < 16; ++i) {
      nn0 = fmaf(c0[i], c0[i], nn0);
      nn1 = fmaf(c1[i], c1[i], nn1);
      nn2 = fmaf(c2[i], c2[i], nn2);
      nn3 = fmaf(c3[i], c3[i], nn3);
    }
  }

  bool r1 = (l & 1) == 0;   // top role for delta=1 (pairs 0-1, 2-3)
  bool r2 = (l & 2) == 0;   // top role for delta=2 and delta=3

#define INTRA6() { rot2(c0,c1,nn0,nn1); rot2(c2,c3,nn2,nn3); \
                   rot2(c0,c2,nn0,nn2); rot2(c1,c3,nn1,nn3); \
                   rot2(c0,c3,nn0,nn3); rot2(c1,c2,nn1,nn2); }

  for (int sw = 0; sw < SWEEPS; ++sw) {
    // cross-lane phases (same-x pairs), done in slope-0 layout
    xrot<0xB1>(c0, nn0, r1); xrot<0xB1>(c1, nn1, r1);
    xrot<0xB1>(c2, nn2, r1); xrot<0xB1>(c3, nn3, r1);
    xrot<0x4E>(c0, nn0, r2); xrot<0x4E>(c1, nn1, r2);
    xrot<0x4E>(c2, nn2, r2); xrot<0x4E>(c3, nn3, r2);
    xrot<0x1B>(c0, nn0, r2); xrot<0x1B>(c1, nn1, r2);
    xrot<0x1B>(c2, nn2, r2); xrot<0x1B>(c3, nn3, r2);

    INTRA6();                                   // slope 0
    // slope0 -> slope1 (delta=1): slot s moves by XOR mul(1,s)=s
    tmov<0xB1>(c1, nn1); tmov<0x4E>(c2, nn2); tmov<0x1B>(c3, nn3);
    INTRA6();                                   // slope 1
    // slope1 -> slope2 (delta=3): slot s moves by XOR mul(3,s) = 3,1,2
    tmov<0x1B>(c1, nn1); tmov<0xB1>(c2, nn2); tmov<0x4E>(c3, nn3);
    INTRA6();                                   // slope 2
    // slope2 -> slope3 (delta=1)
    tmov<0xB1>(c1, nn1); tmov<0x4E>(c2, nn2); tmov<0x1B>(c3, nn3);
    INTRA6();                                   // slope 3
    // slope3 -> slope0 (delta=3)
    tmov<0x1B>(c1, nn1); tmov<0xB1>(c2, nn2); tmov<0x4E>(c3, nn3);
  }
#undef INTRA6

  // exact final norms (4 per lane), reduce across the quad
  float n2_0 = 0.f, n2_1 = 0.f, n2_2 = 0.f, n2_3 = 0.f;
#pragma unroll
  for (int i = 0; i < 16; ++i) {
    n2_0 = fmaf(c0[i], c0[i], n2_0);
    n2_1 = fmaf(c1[i], c1[i], n2_1);
    n2_2 = fmaf(c2[i], c2[i], n2_2);
    n2_3 = fmaf(c3[i], c3[i], n2_3);
  }
  float s0 = fsqrt_fast(n2_0), s1 = fsqrt_fast(n2_1);
  float s2 = fsqrt_fast(n2_2), s3 = fsqrt_fast(n2_3);
  float lmin = fminf(fminf(s0, s1), fminf(s2, s3));
  float lmax = fmaxf(fmaxf(s0, s1), fmaxf(s2, s3));
  float lsum = __logf(s0 + EPSF) + __logf(s1 + EPSF) +
               __logf(s2 + EPSF) + __logf(s3 + EPSF);
  // quad reduce via XOR dpp
  lmin = fminf(lmin, dppf<0xB1>(lmin));
  lmax = fmaxf(lmax, dppf<0xB1>(lmax));
  lsum += dppf<0xB1>(lsum);
  lmin = fminf(lmin, dppf<0x4E>(lmin));
  lmax = fmaxf(lmax, dppf<0x4E>(lmax));
  lsum += dppf<0x4E>(lsum);
  if (l == 0) {
    float* sp = Sign + (((b * 64 + n) * 64 + m) * 6) * 16 + k;
    sp[0]  = det;
    sp[16] = trace;
    sp[32] = lsum;
    sp[48] = lmin;
    sp[64] = lmax;
  }
}

// ---------------- rho: repeated squaring, quad_perm broadcast, no LDS ----------------
template <int SRCL>
__device__ __forceinline__ void rho_quarter(float (&a)[4][16], float (&acc)[4][16]) {
  constexpr int CTRL = SRCL | (SRCL << 2) | (SRCL << 4) | (SRCL << 6);  // quad bcast
#pragma unroll
  for (int c = 0; c < 4; ++c) {        // global column kk = SRCL*4 + c
    float colk[16];
#pragma unroll
    for (int i = 0; i < 16; ++i) colk[i] = dppf<CTRL>(a[c][i]);  // A[i][kk]
#pragma unroll
    for (int jj = 0; jj < 4; ++jj) {
      float f = a[jj][SRCL * 4 + c];   // A[kk][own col jj] (static index)
#pragma unroll
      for (int i = 0; i < 16; ++i) acc[jj][i] = fmaf(colk[i], f, acc[jj][i]);
    }
  }
}

__global__ __launch_bounds__(128) void k_rho(const float* __restrict__ Q,
                                             const float* __restrict__ K,
                                             const float* __restrict__ T,
                                             float* __restrict__ Sign) {
  int gtid = blockIdx.x * 128 + threadIdx.x;
  int gid = gtid >> 2;              // matrix id, < 131072
  int l = threadIdx.x & 3;
  int k = gid & 15, m = (gid >> 4) & 63, n = (gid >> 10) & 63, b = gid >> 16;
  const float* qrow = Q + (b * 64 + n) * 16;
  const float* krow = K + (b * 64 + m) * 16;

  float a[4][16];
#pragma unroll
  for (int jj = 0; jj < 4; ++jj) {
    int j = 4 * l + jj;
    float w = qrow[j] * krow[j];
#pragma unroll
    for (int i = 0; i < 16; ++i) a[jj][i] = T[i * 256 + j * 16 + k] * w;
  }

  float L = 0.0f, wgt = 0.5f;
  for (int it = 0; it <= RHO_J; ++it) {
    // 4-chain split of the 64-element squared-norm reduction
    float p0 = 0.f, p1 = 0.f, p2 = 0.f, p3 = 0.f;
#pragma unroll
    for (int i = 0; i < 16; ++i) {
      p0 = fmaf(a[0][i], a[0][i], p0);
      p1 = fmaf(a[1][i], a[1][i], p1);
      p2 = fmaf(a[2][i], a[2][i], p2);
      p3 = fmaf(a[3][i], a[3][i], p3);
    }
    float ss = (p0 + p1) + (p2 + p3);
    ss += dppf<0xB1>(ss);
    ss += dppf<0x4E>(ss);
    L = fmaf(__logf(ss), wgt, L);
    wgt *= 0.5f;
    if (it == RHO_J) break;
    float s = (ss > 0.0f) ? frcp_fast(ss) : 0.0f;

    float acc[4][16];
#pragma unroll
    for (int jj = 0; jj < 4; ++jj)
#pragma unroll
      for (int i = 0; i < 16; ++i) acc[jj][i] = 0.f;

    rho_quarter<0>(a, acc);
    rho_quarter<1>(a, acc);
    rho_quarter<2>(a, acc);
    rho_quarter<3>(a, acc);

#pragma unroll
    for (int jj = 0; jj < 4; ++jj)
#pragma unroll
      for (int i = 0; i < 16; ++i) a[jj][i] = acc[jj][i] * s;
  }
  float rho = __expf(L);
  if (l == 0) Sign[(((b * 64 + n) * 64 + m) * 6 + 5) * 16 + k] = rho;
}

// ---------------- out[b,n,v] = sum_{m,s,k} Sign * V ----------------
__global__ __launch_bounds__(256) void k_out(const float* __restrict__ Sign,
                                             const float* __restrict__ V,
                                             float* __restrict__ out) {
  __shared__ float red[256];
  int bn = blockIdx.x;              // 0..127
  int b = bn >> 6;
  int t = threadIdx.x;
  int v = t & 15, mc = t >> 4;      // m in [mc*4, mc*4+4)
  const float* sp = Sign + bn * 6144;
  const float* vp = V + b * 98304;
  float acc = 0.f;
  for (int mm = 0; mm < 4; ++mm) {
    int m = mc * 4 + mm;
    const float* sr = sp + m * 96;
    const float* vr = vp + m * 1536 + v;
#pragma unroll
    for (int sk = 0; sk < 96; ++sk) acc = fmaf(sr[sk], vr[sk * 16], acc);
  }
  red[t] = acc;
  __syncthreads();
  for (int off = 128; off >= 16; off >>= 1) {
    if (t < off) red[t] += red[t + off];
    __syncthreads();
  }
  if (t < 16) out[bn * 16 + t] = red[t];
}

extern "C" void kernel_launch(void* const* d_in, const int* in_sizes, int n_in,
                              void* d_out, int out_size, void* d_ws, size_t ws_size,
                              hipStream_t stream) {
  const float* X  = (const float*)d_in[0];
  const float* Wk = (const float*)d_in[1];
  const float* Wq = (const float*)d_in[2];
  const float* T  = (const float*)d_in[3];
  const float* Wv = (const float*)d_in[4];
  float* out = (float*)d_out;
  float* ws = (float*)d_ws;

  float* Q    = ws + WS_Q;
  float* K    = ws + WS_K;
  float* detT = ws + WS_DETT;
  float* V    = ws + WS_V;
  float* Sign = ws + WS_SIGN;

  hipLaunchKernelGGL(k_qk,   dim3(8),    dim3(256), 0, stream, X, Wk, Wq, Q, K);
  hipLaunchKernelGGL(k_dett, dim3(1),    dim3(64),  0, stream, T, detT);
  hipLaunchKernelGGL(k_v,    dim3(768),  dim3(256), 0, stream, X, Wv, V);
  hipLaunchKernelGGL(k_svd,  dim3(2048), dim3(256), 0, stream, Q, K, T, detT, Sign);
  hipLaunchKernelGGL(k_rho,  dim3(4096), dim3(128), 0, stream, Q, K, T, Sign);
  hipLaunchKernelGGL(k_out,  dim3(128),  dim3(256), 0, stream, Sign, V, out);
}

// Round 7
// 527.808 us; speedup vs baseline: 2.8257x; 1.0861x over previous
//
#include <hip/hip_runtime.h>
#include <math.h>

// Problem: B=2, N=64, D=16.
// C_{b,n,m,k} = diag(Q_n) T_k diag(K_m), 131072 16x16 matrices.
// det/trace closed-form; sigma via one-sided block-Jacobi (4 lanes x 4 cols,
// GF(4) spread schedule, all comm = 1-inst mov_dpp); rho via normalized
// repeated squaring with quad_perm broadcast + geometric tail correction.
// R7: 3-transcendental rot_coeff, RHO_J=10 w/ doubled tail term, fused setup.

#define EPSF 1e-6f
#define SWEEPS 6
#define RHO_J 10

// workspace float offsets
#define WS_Q    0         // [2][64][16]            = 2048
#define WS_K    2048      // [2][64][16]            = 2048
#define WS_DETT 4096      // [16]
#define WS_V    4352      // [2][64][6][16][16]     = 196608
#define WS_SIGN 200960    // [2][64][64][6][16]     = 786432

// quad_perm DPP: ctrl = p0|p1<<2|p2<<4|p3<<6; XOR masks: 1->0xB1, 2->0x4E, 3->0x1B
template <int CTRL>
__device__ __forceinline__ float dppf(float v) {
  return __int_as_float(__builtin_amdgcn_mov_dpp(__float_as_int(v), CTRL, 0xF, 0xF, true));
}
__device__ __forceinline__ float fsqrt_fast(float x) { return __builtin_amdgcn_sqrtf(x); }
__device__ __forceinline__ float frcp_fast(float x)  { return __builtin_amdgcn_rcpf(x); }
__device__ __forceinline__ float frsq_fast(float x)  { return __builtin_amdgcn_rsqf(x); }

// ---------------- fused setup: V (768 blocks) | QK (8 blocks) | detT (1 block) ----------------
__global__ __launch_bounds__(256) void k_setup(const float* __restrict__ X,
                                               const float* __restrict__ Wk,
                                               const float* __restrict__ Wq,
                                               const float* __restrict__ T,
                                               const float* __restrict__ Wv,
                                               float* __restrict__ Q,
                                               float* __restrict__ Kout,
                                               float* __restrict__ detT,
                                               float* __restrict__ V) {
  int blk = blockIdx.x;
  if (blk < 768) {
    int t = blk * 256 + threadIdx.x;          // 196608 threads for V
    int bm = t / 1536; int rem = t - bm * 1536;
    int s = rem >> 8; int kk = (rem >> 4) & 15; int v = rem & 15;
    const float* x = X + bm * 16;
    float acc = 0.f;
#pragma unroll
    for (int d = 0; d < 16; ++d) acc += x[d] * Wv[((d * 6 + s) * 16 + kk) * 16 + v];
    V[t] = acc;
  } else if (blk < 776) {
    int t = (blk - 768) * 256 + threadIdx.x;  // 2048 threads for Q,K
    int i = t & 15, bn = t >> 4;
    const float* x = X + bn * 16;
    float q = 0.f, kk = 0.f;
#pragma unroll
    for (int d = 0; d < 16; ++d) {
      float xv = x[d];
      q  += xv * Wq[d * 16 + i];
      kk += xv * Wk[d * 16 + i];
    }
    Q[t] = q; Kout[t] = kk;
  } else {
    // det(T_k) via LU with partial pivoting
    __shared__ float A[16][16][16];  // [k][i][j]
    for (int idx = threadIdx.x; idx < 4096; idx += 256) {
      int i = idx >> 8, j = (idx >> 4) & 15, kk = idx & 15;
      A[kk][i][j] = T[idx];          // T[i,j,k] at i*256+j*16+k
    }
    __syncthreads();
    int k = threadIdx.x;
    if (k < 16) {
      float det = 1.0f;
      for (int c = 0; c < 16; ++c) {
        int p = c; float mx = fabsf(A[k][c][c]);
        for (int r = c + 1; r < 16; ++r) {
          float v = fabsf(A[k][r][c]);
          if (v > mx) { mx = v; p = r; }
        }
        if (mx == 0.0f) { det = 0.0f; break; }
        if (p != c) {
          det = -det;
          for (int cc = c; cc < 16; ++cc) {
            float tmp = A[k][c][cc]; A[k][c][cc] = A[k][p][cc]; A[k][p][cc] = tmp;
          }
        }
        float piv = A[k][c][c];
        det *= piv;
        float inv = 1.0f / piv;
        for (int r = c + 1; r < 16; ++r) {
          float f = A[k][r][c] * inv;
          for (int cc = c + 1; cc < 16; ++cc) A[k][r][cc] -= f * A[k][c][cc];
        }
      }
      detT[k] = det;
    }
  }
}

// ---------------- Jacobi helpers ----------------
// t = 2g / ((be-al) + copysign(h, be-al)), h = sqrt((be-al)^2 + 4g^2)
// == sign(zeta)/(|zeta|+sqrt(1+zeta^2)), zeta=(be-al)/2g.  3 transcendentals.
__device__ __forceinline__ void rot_coeff(float al, float be, float ga,
                                          float& cc, float& ss, float& tg) {
  float w = be - al;
  float v = ga + ga;
  float h = fsqrt_fast(fmaf(w, w, v * v));
  float t = v * frcp_fast(w + copysignf(h, w));
  t = (ga == 0.0f) ? 0.0f : t;     // kill NaN from 0/0 (w<=0, ga=0 path)
  cc = frsq_fast(fmaf(t, t, 1.0f));
  ss = cc * t;
  tg = t * ga;
}

// lane-local rotation of columns a (top) / b (bottom) with carried norms
__device__ __forceinline__ void rot2(float (&a)[16], float (&b)[16],
                                     float& na, float& nb) {
  float g0 = 0.f, g1 = 0.f;
#pragma unroll
  for (int i = 0; i < 8; ++i) {
    g0 = fmaf(a[i], b[i], g0);
    g1 = fmaf(a[i + 8], b[i + 8], g1);
  }
  float ga = g0 + g1;
  float cc, ss, tg; rot_coeff(na, nb, ga, cc, ss, tg);
  float ns = -ss;
#pragma unroll
  for (int i = 0; i < 16; ++i) {
    float ti = a[i], bi = b[i];
    a[i] = fmaf(ns, bi, cc * ti);
    b[i] = fmaf(ss, ti, cc * bi);
  }
  na -= tg; nb += tg;
}

// cross-lane rotation: pair = (own col, partner-lane col at same slot).
// Both lanes compute bit-identical coefficients; role picks top/bottom.
template <int CTRL>
__device__ __forceinline__ void xrot(float (&a)[16], float& na, bool top) {
  float oth[16];
#pragma unroll
  for (int i = 0; i < 16; ++i) oth[i] = dppf<CTRL>(a[i]);
  float on = dppf<CTRL>(na);
  float al = top ? na : on, be = top ? on : na;
  float g0 = 0.f, g1 = 0.f;
#pragma unroll
  for (int i = 0; i < 8; ++i) {
    g0 = fmaf(a[i], oth[i], g0);
    g1 = fmaf(a[i + 8], oth[i + 8], g1);
  }
  float ga = g0 + g1;
  float cc, ss, tg; rot_coeff(al, be, ga, cc, ss, tg);
  float s2 = top ? -ss : ss;
#pragma unroll
  for (int i = 0; i < 16; ++i) a[i] = fmaf(s2, oth[i], cc * a[i]);
  na += top ? -tg : tg;
}

// config-transition move of one slot's column+norm (XOR within quad)
template <int CTRL>
__device__ __forceinline__ void tmov(float (&a)[16], float& na) {
#pragma unroll
  for (int i = 0; i < 16; ++i) a[i] = dppf<CTRL>(a[i]);
  na = dppf<CTRL>(na);
}

// ---------------- SVD features + det + trace ----------------
// 4 lanes/matrix (one quad), 4 cols/lane. Per sweep (120 pairs, each once):
// 3 cross-XOR phases (24 same-x pairs) + 4 slope configs (96 local pairs).
__global__ __launch_bounds__(256) void k_svd(const float* __restrict__ Q,
                                             const float* __restrict__ K,
                                             const float* __restrict__ T,
                                             const float* __restrict__ detT,
                                             float* __restrict__ Sign) {
  int gtid = blockIdx.x * 256 + threadIdx.x;
  int gid = gtid >> 2;          // matrix id, < 131072
  int l = threadIdx.x & 3;      // quad lane = group id
  int k = gid & 15, m = (gid >> 4) & 63, n = (gid >> 10) & 63, b = gid >> 16;
  const float* qrow = Q + (b * 64 + n) * 16;
  const float* krow = K + (b * 64 + m) * 16;

  float qv[16];
#pragma unroll
  for (int i = 0; i < 16; ++i) qv[i] = qrow[i];

  float trace = 0.f, pq = 1.f, pk = 1.f;
#pragma unroll
  for (int i = 0; i < 16; ++i) {
    float kv = krow[i];
    pq *= qv[i]; pk *= kv;
    trace += qv[i] * kv * T[i * 272 + k];   // T[i,i,k]
  }
  float det = pq * pk * detT[k];

  // init in slope-0 config: slot s holds col (x=s, y=l), col index 4s+l
  float c0[16], c1[16], c2[16], c3[16];
  float nn0, nn1, nn2, nn3;
  {
    int j0 = l, j1 = 4 + l, j2 = 8 + l, j3 = 12 + l;
    float k0 = krow[j0], k1 = krow[j1], k2 = krow[j2], k3 = krow[j3];
#pragma unroll
    for (int i = 0; i < 16; ++i) {
      float qi = qv[i];
      c0[i] = qi * T[i * 256 + j0 * 16 + k] * k0;
      c1[i] = qi * T[i * 256 + j1 * 16 + k] * k1;
      c2[i] = qi * T[i * 256 + j2 * 16 + k] * k2;
      c3[i] = qi * T[i * 256 + j3 * 16 + k] * k3;
    }
    nn0 = nn1 = nn2 = nn3 = 0.f;
#pragma unroll
    for (int i = 0; i < 16; ++i) {
      nn0 = fmaf(c0[i], c0[i], nn0);
      nn1 = fmaf(c1[i], c1[i], nn1);
      nn2 = fmaf(c2[i], c2[i], nn2);
      nn3 = fmaf(c3[i], c3[i], nn3);
    }
  }

  bool r1 = (l & 1) == 0;   // top role for delta=1
  bool r2 = (l & 2) == 0;   // top role for delta=2 and delta=3

#define INTRA6() { rot2(c0,c1,nn0,nn1); rot2(c2,c3,nn2,nn3); \
                   rot2(c0,c2,nn0,nn2); rot2(c1,c3,nn1,nn3); \
                   rot2(c0,c3,nn0,nn3); rot2(c1,c2,nn1,nn2); }

  for (int sw = 0; sw < SWEEPS; ++sw) {
    // cross-lane phases (same-x pairs), done in slope-0 layout
    xrot<0xB1>(c0, nn0, r1); xrot<0xB1>(c1, nn1, r1);
    xrot<0xB1>(c2, nn2, r1); xrot<0xB1>(c3, nn3, r1);
    xrot<0x4E>(c0, nn0, r2); xrot<0x4E>(c1, nn1, r2);
    xrot<0x4E>(c2, nn2, r2); xrot<0x4E>(c3, nn3, r2);
    xrot<0x1B>(c0, nn0, r2); xrot<0x1B>(c1, nn1, r2);
    xrot<0x1B>(c2, nn2, r2); xrot<0x1B>(c3, nn3, r2);

    INTRA6();                                   // slope 0
    tmov<0xB1>(c1, nn1); tmov<0x4E>(c2, nn2); tmov<0x1B>(c3, nn3);
    INTRA6();                                   // slope 1
    tmov<0x1B>(c1, nn1); tmov<0xB1>(c2, nn2); tmov<0x4E>(c3, nn3);
    INTRA6();                                   // slope 2
    tmov<0xB1>(c1, nn1); tmov<0x4E>(c2, nn2); tmov<0x1B>(c3, nn3);
    INTRA6();                                   // slope 3
    tmov<0x1B>(c1, nn1); tmov<0xB1>(c2, nn2); tmov<0x4E>(c3, nn3);
  }
#undef INTRA6

  // exact final norms (4 per lane), reduce across the quad
  float n2_0 = 0.f, n2_1 = 0.f, n2_2 = 0.f, n2_3 = 0.f;
#pragma unroll
  for (int i = 0; i < 16; ++i) {
    n2_0 = fmaf(c0[i], c0[i], n2_0);
    n2_1 = fmaf(c1[i], c1[i], n2_1);
    n2_2 = fmaf(c2[i], c2[i], n2_2);
    n2_3 = fmaf(c3[i], c3[i], n2_3);
  }
  float s0 = fsqrt_fast(n2_0), s1 = fsqrt_fast(n2_1);
  float s2 = fsqrt_fast(n2_2), s3 = fsqrt_fast(n2_3);
  float lmin = fminf(fminf(s0, s1), fminf(s2, s3));
  float lmax = fmaxf(fmaxf(s0, s1), fmaxf(s2, s3));
  float lsum = __logf(s0 + EPSF) + __logf(s1 + EPSF) +
               __logf(s2 + EPSF) + __logf(s3 + EPSF);
  lmin = fminf(lmin, dppf<0xB1>(lmin));
  lmax = fmaxf(lmax, dppf<0xB1>(lmax));
  lsum += dppf<0xB1>(lsum);
  lmin = fminf(lmin, dppf<0x4E>(lmin));
  lmax = fmaxf(lmax, dppf<0x4E>(lmax));
  lsum += dppf<0x4E>(lsum);
  if (l == 0) {
    float* sp = Sign + (((b * 64 + n) * 64 + m) * 6) * 16 + k;
    sp[0]  = det;
    sp[16] = trace;
    sp[32] = lsum;
    sp[48] = lmin;
    sp[64] = lmax;
  }
}

// ---------------- rho: repeated squaring, quad_perm broadcast, no LDS ----------------
template <int SRCL>
__device__ __forceinline__ void rho_quarter(float (&a)[4][16], float (&acc)[4][16]) {
  constexpr int CTRL = SRCL | (SRCL << 2) | (SRCL << 4) | (SRCL << 6);  // quad bcast
#pragma unroll
  for (int c = 0; c < 4; ++c) {        // global column kk = SRCL*4 + c
    float colk[16];
#pragma unroll
    for (int i = 0; i < 16; ++i) colk[i] = dppf<CTRL>(a[c][i]);  // A[i][kk]
#pragma unroll
    for (int jj = 0; jj < 4; ++jj) {
      float f = a[jj][SRCL * 4 + c];   // A[kk][own col jj] (static index)
#pragma unroll
      for (int i = 0; i < 16; ++i) acc[jj][i] = fmaf(colk[i], f, acc[jj][i]);
    }
  }
}

__global__ __launch_bounds__(128) void k_rho(const float* __restrict__ Q,
                                             const float* __restrict__ K,
                                             const float* __restrict__ T,
                                             float* __restrict__ Sign) {
  int gtid = blockIdx.x * 128 + threadIdx.x;
  int gid = gtid >> 2;              // matrix id, < 131072
  int l = threadIdx.x & 3;
  int k = gid & 15, m = (gid >> 4) & 63, n = (gid >> 10) & 63, b = gid >> 16;
  const float* qrow = Q + (b * 64 + n) * 16;
  const float* krow = K + (b * 64 + m) * 16;

  float a[4][16];
#pragma unroll
  for (int jj = 0; jj < 4; ++jj) {
    int j = 4 * l + jj;
    float w = qrow[j] * krow[j];
#pragma unroll
    for (int i = 0; i < 16; ++i) a[jj][i] = T[i * 256 + j * 16 + k] * w;
  }

  // L = sum_{i<J} log(ss_i)*2^-(i+1) + log(ss_J)*2^-J  (geometric tail:
  // at the normalized-squaring fixed point rho(B*) = ss*, so the tail
  // sum collapses to doubling the last term's weight).
  float L = 0.0f, wgt = 0.5f;
  for (int it = 0; it <= RHO_J; ++it) {
    float p0 = 0.f, p1 = 0.f, p2 = 0.f, p3 = 0.f;
#pragma unroll
    for (int i = 0; i < 16; ++i) {
      p0 = fmaf(a[0][i], a[0][i], p0);
      p1 = fmaf(a[1][i], a[1][i], p1);
      p2 = fmaf(a[2][i], a[2][i], p2);
      p3 = fmaf(a[3][i], a[3][i], p3);
    }
    float ss = (p0 + p1) + (p2 + p3);
    ss += dppf<0xB1>(ss);
    ss += dppf<0x4E>(ss);
    float w2 = (it == RHO_J) ? (wgt + wgt) : wgt;
    L = fmaf(__logf(ss), w2, L);
    wgt *= 0.5f;
    if (it == RHO_J) break;
    float s = (ss > 0.0f) ? frcp_fast(ss) : 0.0f;

    float acc[4][16];
#pragma unroll
    for (int jj = 0; jj < 4; ++jj)
#pragma unroll
      for (int i = 0; i < 16; ++i) acc[jj][i] = 0.f;

    rho_quarter<0>(a, acc);
    rho_quarter<1>(a, acc);
    rho_quarter<2>(a, acc);
    rho_quarter<3>(a, acc);

#pragma unroll
    for (int jj = 0; jj < 4; ++jj)
#pragma unroll
      for (int i = 0; i < 16; ++i) a[jj][i] = acc[jj][i] * s;
  }
  float rho = __expf(L);
  if (l == 0) Sign[(((b * 64 + n) * 64 + m) * 6 + 5) * 16 + k] = rho;
}

// ---------------- out[b,n,v] = sum_{m,s,k} Sign * V ----------------
__global__ __launch_bounds__(256) void k_out(const float* __restrict__ Sign,
                                             const float* __restrict__ V,
                                             float* __restrict__ out) {
  __shared__ float red[256];
  int bn = blockIdx.x;              // 0..127
  int b = bn >> 6;
  int t = threadIdx.x;
  int v = t & 15, mc = t >> 4;      // m in [mc*4, mc*4+4)
  const float* sp = Sign + bn * 6144;
  const float* vp = V + b * 98304;
  float acc = 0.f;
  for (int mm = 0; mm < 4; ++mm) {
    int m = mc * 4 + mm;
    const float* sr = sp + m * 96;
    const float* vr = vp + m * 1536 + v;
#pragma unroll
    for (int sk = 0; sk < 96; ++sk) acc = fmaf(sr[sk], vr[sk * 16], acc);
  }
  red[t] = acc;
  __syncthreads();
  for (int off = 128; off >= 16; off >>= 1) {
    if (t < off) red[t] += red[t + off];
    __syncthreads();
  }
  if (t < 16) out[bn * 16 + t] = red[t];
}

extern "C" void kernel_launch(void* const* d_in, const int* in_sizes, int n_in,
                              void* d_out, int out_size, void* d_ws, size_t ws_size,
                              hipStream_t stream) {
  const float* X  = (const float*)d_in[0];
  const float* Wk = (const float*)d_in[1];
  const float* Wq = (const float*)d_in[2];
  const float* T  = (const float*)d_in[3];
  const float* Wv = (const float*)d_in[4];
  float* out = (float*)d_out;
  float* ws = (float*)d_ws;

  float* Q    = ws + WS_Q;
  float* K    = ws + WS_K;
  float* detT = ws + WS_DETT;
  float* V    = ws + WS_V;
  float* Sign = ws + WS_SIGN;

  hipLaunchKernelGGL(k_setup, dim3(777),  dim3(256), 0, stream,
                     X, Wk, Wq, T, Wv, Q, K, detT, V);
  hipLaunchKernelGGL(k_svd,   dim3(2048), dim3(256), 0, stream, Q, K, T, detT, Sign);
  hipLaunchKernelGGL(k_rho,   dim3(4096), dim3(128), 0, stream, Q, K, T, Sign);
  hipLaunchKernelGGL(k_out,   dim3(128),  dim3(256), 0, stream, Sign, V, out);
}

// Round 8
// 521.911 us; speedup vs baseline: 2.8577x; 1.0113x over previous
//
#include <hip/hip_runtime.h>
#include <math.h>

// Problem: B=2, N=64, D=16.
// C_{b,n,m,k} = diag(Q_n) T_k diag(K_m), 131072 16x16 matrices.
// det/trace closed-form; sigma via one-sided block-Jacobi (4 lanes x 4 cols,
// GF(4) spread schedule, comm = 1-inst mov_dpp) with FAST SCALED ROTATIONS
// (columns stored unscaled, per-column scale d & reciprocal id; 2 FMA/elem
// instead of 4); rho via normalized repeated squaring + geometric tail.

#define EPSF 1e-6f
#define SWEEPS 6
#define RHO_J 10

// workspace float offsets
#define WS_Q    0         // [2][64][16]            = 2048
#define WS_K    2048      // [2][64][16]            = 2048
#define WS_DETT 4096      // [16]
#define WS_V    4352      // [2][64][6][16][16]     = 196608
#define WS_SIGN 200960    // [2][64][64][6][16]     = 786432

// quad_perm DPP: ctrl = p0|p1<<2|p2<<4|p3<<6; XOR masks: 1->0xB1, 2->0x4E, 3->0x1B
template <int CTRL>
__device__ __forceinline__ float dppf(float v) {
  return __int_as_float(__builtin_amdgcn_mov_dpp(__float_as_int(v), CTRL, 0xF, 0xF, true));
}
__device__ __forceinline__ float fsqrt_fast(float x) { return __builtin_amdgcn_sqrtf(x); }
__device__ __forceinline__ float frcp_fast(float x)  { return __builtin_amdgcn_rcpf(x); }
__device__ __forceinline__ float frsq_fast(float x)  { return __builtin_amdgcn_rsqf(x); }

// ---------------- fused setup: V (768 blocks) | QK (8 blocks) | detT (1 block) ----------------
__global__ __launch_bounds__(256) void k_setup(const float* __restrict__ X,
                                               const float* __restrict__ Wk,
                                               const float* __restrict__ Wq,
                                               const float* __restrict__ T,
                                               const float* __restrict__ Wv,
                                               float* __restrict__ Q,
                                               float* __restrict__ Kout,
                                               float* __restrict__ detT,
                                               float* __restrict__ V) {
  int blk = blockIdx.x;
  if (blk < 768) {
    int t = blk * 256 + threadIdx.x;          // 196608 threads for V
    int bm = t / 1536; int rem = t - bm * 1536;
    int s = rem >> 8; int kk = (rem >> 4) & 15; int v = rem & 15;
    const float* x = X + bm * 16;
    float acc = 0.f;
#pragma unroll
    for (int d = 0; d < 16; ++d) acc += x[d] * Wv[((d * 6 + s) * 16 + kk) * 16 + v];
    V[t] = acc;
  } else if (blk < 776) {
    int t = (blk - 768) * 256 + threadIdx.x;  // 2048 threads for Q,K
    int i = t & 15, bn = t >> 4;
    const float* x = X + bn * 16;
    float q = 0.f, kk = 0.f;
#pragma unroll
    for (int d = 0; d < 16; ++d) {
      float xv = x[d];
      q  += xv * Wq[d * 16 + i];
      kk += xv * Wk[d * 16 + i];
    }
    Q[t] = q; Kout[t] = kk;
  } else {
    // det(T_k) via LU with partial pivoting
    __shared__ float A[16][16][16];  // [k][i][j]
    for (int idx = threadIdx.x; idx < 4096; idx += 256) {
      int i = idx >> 8, j = (idx >> 4) & 15, kk = idx & 15;
      A[kk][i][j] = T[idx];          // T[i,j,k] at i*256+j*16+k
    }
    __syncthreads();
    int k = threadIdx.x;
    if (k < 16) {
      float det = 1.0f;
      for (int c = 0; c < 16; ++c) {
        int p = c; float mx = fabsf(A[k][c][c]);
        for (int r = c + 1; r < 16; ++r) {
          float v = fabsf(A[k][r][c]);
          if (v > mx) { mx = v; p = r; }
        }
        if (mx == 0.0f) { det = 0.0f; break; }
        if (p != c) {
          det = -det;
          for (int cc = c; cc < 16; ++cc) {
            float tmp = A[k][c][cc]; A[k][c][cc] = A[k][p][cc]; A[k][p][cc] = tmp;
          }
        }
        float piv = A[k][c][c];
        det *= piv;
        float inv = 1.0f / piv;
        for (int r = c + 1; r < 16; ++r) {
          float f = A[k][r][c] * inv;
          for (int cc = c + 1; cc < 16; ++cc) A[k][r][cc] -= f * A[k][c][cc];
        }
      }
      detT[k] = det;
    }
  }
}

// ---------------- fast scaled Jacobi helpers ----------------
// Actual column = d * stored column. True rotation A'=cA-sB, B'=sA+cB becomes:
//   a' = a - t*(db/da)*b,  b' = b + t*(da/db)*a,  da*=c, db*=c.
// Norms na,nb are TRUE squared norms (Rutishauser-carried). 1/c = (1+t^2)*rsq(1+t^2).

// lane-local fast rotation
__device__ __forceinline__ void rot2(float (&a)[16], float (&b)[16],
                                     float& na, float& nb,
                                     float& da, float& ida,
                                     float& db, float& idb) {
  float g0 = 0.f, g1 = 0.f;
#pragma unroll
  for (int i = 0; i < 8; ++i) {
    g0 = fmaf(a[i], b[i], g0);
    g1 = fmaf(a[i + 8], b[i + 8], g1);
  }
  float ga = (da * db) * (g0 + g1);   // true gamma
  float w = nb - na;
  float v = ga + ga;
  float h = fsqrt_fast(fmaf(w, w, v * v));
  float t = v * frcp_fast(w + copysignf(h, w));
  t = (ga == 0.0f) ? 0.0f : t;
  float p = fmaf(t, t, 1.0f);
  float cc = frsq_fast(p);
  float icc = p * cc;                 // 1/cc
  float tg = t * ga;
  float t1 = -t * (db * ida);
  float t2 =  t * (da * idb);
#pragma unroll
  for (int i = 0; i < 16; ++i) {
    float ai = a[i];
    a[i] = fmaf(t1, b[i], ai);
    b[i] = fmaf(t2, ai, b[i]);
  }
  na -= tg; nb += tg;
  da *= cc; db *= cc; ida *= icc; idb *= icc;
}

// cross-lane fast rotation: partner column at same slot in XOR-partner lane.
// Both lanes compute bit-identical coefficients (products commute).
template <int CTRL>
__device__ __forceinline__ void xrot(float (&a)[16], float& na,
                                     float& d, float& id, bool top) {
  float oth[16];
#pragma unroll
  for (int i = 0; i < 16; ++i) oth[i] = dppf<CTRL>(a[i]);
  float on = dppf<CTRL>(na);
  float od = dppf<CTRL>(d);
  float al = top ? na : on, be = top ? on : na;
  float g0 = 0.f, g1 = 0.f;
#pragma unroll
  for (int i = 0; i < 8; ++i) {
    g0 = fmaf(a[i], oth[i], g0);
    g1 = fmaf(a[i + 8], oth[i + 8], g1);
  }
  float ga = (d * od) * (g0 + g1);
  float w = be - al;
  float v = ga + ga;
  float h = fsqrt_fast(fmaf(w, w, v * v));
  float t = v * frcp_fast(w + copysignf(h, w));
  t = (ga == 0.0f) ? 0.0f : t;
  float p = fmaf(t, t, 1.0f);
  float cc = frsq_fast(p);
  float icc = p * cc;
  float tg = t * ga;
  float coef = (top ? -t : t) * (od * id);
#pragma unroll
  for (int i = 0; i < 16; ++i) a[i] = fmaf(coef, oth[i], a[i]);
  na += top ? -tg : tg;
  d *= cc; id *= icc;
}

// config-transition move of one slot's column+norm+scales (XOR within quad)
template <int CTRL>
__device__ __forceinline__ void tmov(float (&a)[16], float& na,
                                     float& d, float& id) {
#pragma unroll
  for (int i = 0; i < 16; ++i) a[i] = dppf<CTRL>(a[i]);
  na = dppf<CTRL>(na);
  d = dppf<CTRL>(d);
  id = dppf<CTRL>(id);
}

// ---------------- SVD features + det + trace ----------------
// 4 lanes/matrix (one quad), 4 cols/lane. Per sweep (120 pairs, each once):
// 3 cross-XOR phases (24 same-x pairs) + 4 slope configs (96 local pairs).
__global__ __launch_bounds__(256) void k_svd(const float* __restrict__ Q,
                                             const float* __restrict__ K,
                                             const float* __restrict__ T,
                                             const float* __restrict__ detT,
                                             float* __restrict__ Sign) {
  int gtid = blockIdx.x * 256 + threadIdx.x;
  int gid = gtid >> 2;          // matrix id, < 131072
  int l = threadIdx.x & 3;      // quad lane = group id
  int k = gid & 15, m = (gid >> 4) & 63, n = (gid >> 10) & 63, b = gid >> 16;
  const float* qrow = Q + (b * 64 + n) * 16;
  const float* krow = K + (b * 64 + m) * 16;

  float qv[16];
#pragma unroll
  for (int i = 0; i < 16; ++i) qv[i] = qrow[i];

  float trace = 0.f, pq = 1.f, pk = 1.f;
#pragma unroll
  for (int i = 0; i < 16; ++i) {
    float kv = krow[i];
    pq *= qv[i]; pk *= kv;
    trace += qv[i] * kv * T[i * 272 + k];   // T[i,i,k]
  }
  float det = pq * pk * detT[k];

  // init in slope-0 config: slot s holds col (x=s, y=l), col index 4s+l
  float c0[16], c1[16], c2[16], c3[16];
  float nn0, nn1, nn2, nn3;
  {
    int j0 = l, j1 = 4 + l, j2 = 8 + l, j3 = 12 + l;
    float k0 = krow[j0], k1 = krow[j1], k2 = krow[j2], k3 = krow[j3];
#pragma unroll
    for (int i = 0; i < 16; ++i) {
      float qi = qv[i];
      c0[i] = qi * T[i * 256 + j0 * 16 + k] * k0;
      c1[i] = qi * T[i * 256 + j1 * 16 + k] * k1;
      c2[i] = qi * T[i * 256 + j2 * 16 + k] * k2;
      c3[i] = qi * T[i * 256 + j3 * 16 + k] * k3;
    }
    nn0 = nn1 = nn2 = nn3 = 0.f;
#pragma unroll
    for (int i = 0; i < 16; ++i) {
      nn0 = fmaf(c0[i], c0[i], nn0);
      nn1 = fmaf(c1[i], c1[i], nn1);
      nn2 = fmaf(c2[i], c2[i], nn2);
      nn3 = fmaf(c3[i], c3[i], nn3);
    }
  }
  float d0 = 1.f, d1 = 1.f, d2 = 1.f, d3 = 1.f;
  float i0 = 1.f, i1 = 1.f, i2 = 1.f, i3 = 1.f;

  bool r1 = (l & 1) == 0;   // top role for delta=1
  bool r2 = (l & 2) == 0;   // top role for delta=2 and delta=3

#define INTRA6() { rot2(c0,c1,nn0,nn1,d0,i0,d1,i1); rot2(c2,c3,nn2,nn3,d2,i2,d3,i3); \
                   rot2(c0,c2,nn0,nn2,d0,i0,d2,i2); rot2(c1,c3,nn1,nn3,d1,i1,d3,i3); \
                   rot2(c0,c3,nn0,nn3,d0,i0,d3,i3); rot2(c1,c2,nn1,nn2,d1,i1,d2,i2); }

  for (int sw = 0; sw < SWEEPS; ++sw) {
    // cross-lane phases (same-x pairs), done in slope-0 layout
    xrot<0xB1>(c0, nn0, d0, i0, r1); xrot<0xB1>(c1, nn1, d1, i1, r1);
    xrot<0xB1>(c2, nn2, d2, i2, r1); xrot<0xB1>(c3, nn3, d3, i3, r1);
    xrot<0x4E>(c0, nn0, d0, i0, r2); xrot<0x4E>(c1, nn1, d1, i1, r2);
    xrot<0x4E>(c2, nn2, d2, i2, r2); xrot<0x4E>(c3, nn3, d3, i3, r2);
    xrot<0x1B>(c0, nn0, d0, i0, r2); xrot<0x1B>(c1, nn1, d1, i1, r2);
    xrot<0x1B>(c2, nn2, d2, i2, r2); xrot<0x1B>(c3, nn3, d3, i3, r2);

    INTRA6();                                   // slope 0
    tmov<0xB1>(c1, nn1, d1, i1); tmov<0x4E>(c2, nn2, d2, i2); tmov<0x1B>(c3, nn3, d3, i3);
    INTRA6();                                   // slope 1
    tmov<0x1B>(c1, nn1, d1, i1); tmov<0xB1>(c2, nn2, d2, i2); tmov<0x4E>(c3, nn3, d3, i3);
    INTRA6();                                   // slope 2
    tmov<0xB1>(c1, nn1, d1, i1); tmov<0x4E>(c2, nn2, d2, i2); tmov<0x1B>(c3, nn3, d3, i3);
    INTRA6();                                   // slope 3
    tmov<0x1B>(c1, nn1, d1, i1); tmov<0xB1>(c2, nn2, d2, i2); tmov<0x4E>(c3, nn3, d3, i3);

    // per-sweep rescale: fold scales into columns (bounds dynamic range)
#pragma unroll
    for (int i = 0; i < 16; ++i) {
      c0[i] *= d0; c1[i] *= d1; c2[i] *= d2; c3[i] *= d3;
    }
    d0 = d1 = d2 = d3 = 1.f;
    i0 = i1 = i2 = i3 = 1.f;
  }
#undef INTRA6

  // exact final norms (scales are 1 after rescale), reduce across the quad
  float n2_0 = 0.f, n2_1 = 0.f, n2_2 = 0.f, n2_3 = 0.f;
#pragma unroll
  for (int i = 0; i < 16; ++i) {
    n2_0 = fmaf(c0[i], c0[i], n2_0);
    n2_1 = fmaf(c1[i], c1[i], n2_1);
    n2_2 = fmaf(c2[i], c2[i], n2_2);
    n2_3 = fmaf(c3[i], c3[i], n2_3);
  }
  float s0 = fsqrt_fast(n2_0), s1 = fsqrt_fast(n2_1);
  float s2 = fsqrt_fast(n2_2), s3 = fsqrt_fast(n2_3);
  float lmin = fminf(fminf(s0, s1), fminf(s2, s3));
  float lmax = fmaxf(fmaxf(s0, s1), fmaxf(s2, s3));
  float lsum = __logf(s0 + EPSF) + __logf(s1 + EPSF) +
               __logf(s2 + EPSF) + __logf(s3 + EPSF);
  lmin = fminf(lmin, dppf<0xB1>(lmin));
  lmax = fmaxf(lmax, dppf<0xB1>(lmax));
  lsum += dppf<0xB1>(lsum);
  lmin = fminf(lmin, dppf<0x4E>(lmin));
  lmax = fmaxf(lmax, dppf<0x4E>(lmax));
  lsum += dppf<0x4E>(lsum);
  if (l == 0) {
    float* sp = Sign + (((b * 64 + n) * 64 + m) * 6) * 16 + k;
    sp[0]  = det;
    sp[16] = trace;
    sp[32] = lsum;
    sp[48] = lmin;
    sp[64] = lmax;
  }
}

// ---------------- rho: repeated squaring, quad_perm broadcast, no LDS ----------------
template <int SRCL>
__device__ __forceinline__ void rho_quarter(float (&a)[4][16], float (&acc)[4][16]) {
  constexpr int CTRL = SRCL | (SRCL << 2) | (SRCL << 4) | (SRCL << 6);  // quad bcast
#pragma unroll
  for (int c = 0; c < 4; ++c) {        // global column kk = SRCL*4 + c
    float colk[16];
#pragma unroll
    for (int i = 0; i < 16; ++i) colk[i] = dppf<CTRL>(a[c][i]);  // A[i][kk]
#pragma unroll
    for (int jj = 0; jj < 4; ++jj) {
      float f = a[jj][SRCL * 4 + c];   // A[kk][own col jj] (static index)
#pragma unroll
      for (int i = 0; i < 16; ++i) acc[jj][i] = fmaf(colk[i], f, acc[jj][i]);
    }
  }
}

__global__ __launch_bounds__(128) void k_rho(const float* __restrict__ Q,
                                             const float* __restrict__ K,
                                             const float* __restrict__ T,
                                             float* __restrict__ Sign) {
  int gtid = blockIdx.x * 128 + threadIdx.x;
  int gid = gtid >> 2;              // matrix id, < 131072
  int l = threadIdx.x & 3;
  int k = gid & 15, m = (gid >> 4) & 63, n = (gid >> 10) & 63, b = gid >> 16;
  const float* qrow = Q + (b * 64 + n) * 16;
  const float* krow = K + (b * 64 + m) * 16;

  float a[4][16];
#pragma unroll
  for (int jj = 0; jj < 4; ++jj) {
    int j = 4 * l + jj;
    float w = qrow[j] * krow[j];
#pragma unroll
    for (int i = 0; i < 16; ++i) a[jj][i] = T[i * 256 + j * 16 + k] * w;
  }

  // L = sum_{i<J} log(ss_i)*2^-(i+1) + log(ss_J)*2^-J (geometric tail)
  float L = 0.0f, wgt = 0.5f;
  for (int it = 0; it <= RHO_J; ++it) {
    float p0 = 0.f, p1 = 0.f, p2 = 0.f, p3 = 0.f;
#pragma unroll
    for (int i = 0; i < 16; ++i) {
      p0 = fmaf(a[0][i], a[0][i], p0);
      p1 = fmaf(a[1][i], a[1][i], p1);
      p2 = fmaf(a[2][i], a[2][i], p2);
      p3 = fmaf(a[3][i], a[3][i], p3);
    }
    float ss = (p0 + p1) + (p2 + p3);
    ss += dppf<0xB1>(ss);
    ss += dppf<0x4E>(ss);
    float w2 = (it == RHO_J) ? (wgt + wgt) : wgt;
    L = fmaf(__logf(ss), w2, L);
    wgt *= 0.5f;
    if (it == RHO_J) break;
    float s = (ss > 0.0f) ? frcp_fast(ss) : 0.0f;

    float acc[4][16];
#pragma unroll
    for (int jj = 0; jj < 4; ++jj)
#pragma unroll
      for (int i = 0; i < 16; ++i) acc[jj][i] = 0.f;

    rho_quarter<0>(a, acc);
    rho_quarter<1>(a, acc);
    rho_quarter<2>(a, acc);
    rho_quarter<3>(a, acc);

#pragma unroll
    for (int jj = 0; jj < 4; ++jj)
#pragma unroll
      for (int i = 0; i < 16; ++i) a[jj][i] = acc[jj][i] * s;
  }
  float rho = __expf(L);
  if (l == 0) Sign[(((b * 64 + n) * 64 + m) * 6 + 5) * 16 + k] = rho;
}

// ---------------- out[b,n,v] = sum_{m,s,k} Sign * V ----------------
__global__ __launch_bounds__(256) void k_out(const float* __restrict__ Sign,
                                             const float* __restrict__ V,
                                             float* __restrict__ out) {
  __shared__ float red[256];
  int bn = blockIdx.x;              // 0..127
  int b = bn >> 6;
  int t = threadIdx.x;
  int v = t & 15, mc = t >> 4;      // m in [mc*4, mc*4+4)
  const float* sp = Sign + bn * 6144;
  const float* vp = V + b * 98304;
  float acc = 0.f;
  for (int mm = 0; mm < 4; ++mm) {
    int m = mc * 4 + mm;
    const float* sr = sp + m * 96;
    const float* vr = vp + m * 1536 + v;
#pragma unroll
    for (int sk = 0; sk < 96; ++sk) acc = fmaf(sr[sk], vr[sk * 16], acc);
  }
  red[t] = acc;
  __syncthreads();
  for (int off = 128; off >= 16; off >>= 1) {
    if (t < off) red[t] += red[t + off];
    __syncthreads();
  }
  if (t < 16) out[bn * 16 + t] = red[t];
}

extern "C" void kernel_launch(void* const* d_in, const int* in_sizes, int n_in,
                              void* d_out, int out_size, void* d_ws, size_t ws_size,
                              hipStream_t stream) {
  const float* X  = (const float*)d_in[0];
  const float* Wk = (const float*)d_in[1];
  const float* Wq = (const float*)d_in[2];
  const float* T  = (const float*)d_in[3];
  const float* Wv = (const float*)d_in[4];
  float* out = (float*)d_out;
  float* ws = (float*)d_ws;

  float* Q    = ws + WS_Q;
  float* K    = ws + WS_K;
  float* detT = ws + WS_DETT;
  float* V    = ws + WS_V;
  float* Sign = ws + WS_SIGN;

  hipLaunchKernelGGL(k_setup, dim3(777),  dim3(256), 0, stream,
                     X, Wk, Wq, T, Wv, Q, K, detT, V);
  hipLaunchKernelGGL(k_svd,   dim3(2048), dim3(256), 0, stream, Q, K, T, detT, Sign);
  hipLaunchKernelGGL(k_rho,   dim3(4096), dim3(128), 0, stream, Q, K, T, Sign);
  hipLaunchKernelGGL(k_out,   dim3(128),  dim3(256), 0, stream, Sign, V, out);
}

// Round 9
// 443.569 us; speedup vs baseline: 3.3624x; 1.1766x over previous
//
#include <hip/hip_runtime.h>
#include <math.h>

// Problem: B=2, N=64, D=16.
// C_{b,n,m,k} = diag(Q_n) T_k diag(K_m), 131072 16x16 matrices.
// det/trace closed-form; sigma via one-sided block-Jacobi (4 lanes x 4 cols,
// GF(4) spread schedule, comm = 1-inst mov_dpp, fast scaled rotations);
// rho via normalized repeated squaring + geometric tail.
// R9: PACKED FP32 — columns stored as float2, all hot FMAs via
// __builtin_elementwise_fma on <2 x float> to select v_pk_fma_f32.

#define EPSF 1e-6f
#define SWEEPS 6
#define RHO_J 10

// workspace float offsets
#define WS_Q    0         // [2][64][16]            = 2048
#define WS_K    2048      // [2][64][16]            = 2048
#define WS_DETT 4096      // [16]
#define WS_V    4352      // [2][64][6][16][16]     = 196608
#define WS_SIGN 200960    // [2][64][64][6][16]     = 786432

typedef float v2f __attribute__((ext_vector_type(2)));

// quad_perm DPP: ctrl = p0|p1<<2|p2<<4|p3<<6; XOR masks: 1->0xB1, 2->0x4E, 3->0x1B
template <int CTRL>
__device__ __forceinline__ float dppf(float v) {
  return __int_as_float(__builtin_amdgcn_mov_dpp(__float_as_int(v), CTRL, 0xF, 0xF, true));
}
template <int CTRL>
__device__ __forceinline__ v2f dpp2(v2f v) {
  v2f r;
  r.x = dppf<CTRL>(v.x);
  r.y = dppf<CTRL>(v.y);
  return r;
}
__device__ __forceinline__ v2f pkfma(v2f a, v2f b, v2f c) {
  return __builtin_elementwise_fma(a, b, c);
}
__device__ __forceinline__ v2f bc2(float s) { v2f r; r.x = s; r.y = s; return r; }
__device__ __forceinline__ float fsqrt_fast(float x) { return __builtin_amdgcn_sqrtf(x); }
__device__ __forceinline__ float frcp_fast(float x)  { return __builtin_amdgcn_rcpf(x); }
__device__ __forceinline__ float frsq_fast(float x)  { return __builtin_amdgcn_rsqf(x); }

// ---------------- fused setup: V (768 blocks) | QK (8 blocks) | detT (1 block) ----------------
__global__ __launch_bounds__(256) void k_setup(const float* __restrict__ X,
                                               const float* __restrict__ Wk,
                                               const float* __restrict__ Wq,
                                               const float* __restrict__ T,
                                               const float* __restrict__ Wv,
                                               float* __restrict__ Q,
                                               float* __restrict__ Kout,
                                               float* __restrict__ detT,
                                               float* __restrict__ V) {
  int blk = blockIdx.x;
  if (blk < 768) {
    int t = blk * 256 + threadIdx.x;          // 196608 threads for V
    int bm = t / 1536; int rem = t - bm * 1536;
    int s = rem >> 8; int kk = (rem >> 4) & 15; int v = rem & 15;
    const float* x = X + bm * 16;
    float acc = 0.f;
#pragma unroll
    for (int d = 0; d < 16; ++d) acc += x[d] * Wv[((d * 6 + s) * 16 + kk) * 16 + v];
    V[t] = acc;
  } else if (blk < 776) {
    int t = (blk - 768) * 256 + threadIdx.x;  // 2048 threads for Q,K
    int i = t & 15, bn = t >> 4;
    const float* x = X + bn * 16;
    float q = 0.f, kk = 0.f;
#pragma unroll
    for (int d = 0; d < 16; ++d) {
      float xv = x[d];
      q  += xv * Wq[d * 16 + i];
      kk += xv * Wk[d * 16 + i];
    }
    Q[t] = q; Kout[t] = kk;
  } else {
    // det(T_k) via LU with partial pivoting
    __shared__ float A[16][16][16];  // [k][i][j]
    for (int idx = threadIdx.x; idx < 4096; idx += 256) {
      int i = idx >> 8, j = (idx >> 4) & 15, kk = idx & 15;
      A[kk][i][j] = T[idx];          // T[i,j,k] at i*256+j*16+k
    }
    __syncthreads();
    int k = threadIdx.x;
    if (k < 16) {
      float det = 1.0f;
      for (int c = 0; c < 16; ++c) {
        int p = c; float mx = fabsf(A[k][c][c]);
        for (int r = c + 1; r < 16; ++r) {
          float v = fabsf(A[k][r][c]);
          if (v > mx) { mx = v; p = r; }
        }
        if (mx == 0.0f) { det = 0.0f; break; }
        if (p != c) {
          det = -det;
          for (int cc = c; cc < 16; ++cc) {
            float tmp = A[k][c][cc]; A[k][c][cc] = A[k][p][cc]; A[k][p][cc] = tmp;
          }
        }
        float piv = A[k][c][c];
        det *= piv;
        float inv = 1.0f / piv;
        for (int r = c + 1; r < 16; ++r) {
          float f = A[k][r][c] * inv;
          for (int cc = c + 1; cc < 16; ++cc) A[k][r][cc] -= f * A[k][c][cc];
        }
      }
      detT[k] = det;
    }
  }
}

// ---------------- fast scaled Jacobi helpers (packed) ----------------
// Actual column = d * stored column. a' = a - t*(db/da)*b, b' = b + t*(da/db)*a,
// da*=c, db*=c. Norms na,nb are TRUE squared norms (Rutishauser-carried).

__device__ __forceinline__ void rot2(v2f (&a)[8], v2f (&b)[8],
                                     float& na, float& nb,
                                     float& da, float& ida,
                                     float& db, float& idb) {
  v2f g0 = bc2(0.f), g1 = bc2(0.f);
#pragma unroll
  for (int i = 0; i < 4; ++i) {
    g0 = pkfma(a[i], b[i], g0);
    g1 = pkfma(a[i + 4], b[i + 4], g1);
  }
  v2f g = g0 + g1;
  float ga = (da * db) * (g.x + g.y);   // true gamma
  float w = nb - na;
  float v = ga + ga;
  float h = fsqrt_fast(fmaf(w, w, v * v));
  float t = v * frcp_fast(w + copysignf(h, w));
  t = (ga == 0.0f) ? 0.0f : t;
  float p = fmaf(t, t, 1.0f);
  float cc = frsq_fast(p);
  float icc = p * cc;                 // 1/cc
  float tg = t * ga;
  v2f t1 = bc2(-t * (db * ida));
  v2f t2 = bc2( t * (da * idb));
#pragma unroll
  for (int i = 0; i < 8; ++i) {
    v2f ai = a[i];
    a[i] = pkfma(t1, b[i], ai);
    b[i] = pkfma(t2, ai, b[i]);
  }
  na -= tg; nb += tg;
  da *= cc; db *= cc; ida *= icc; idb *= icc;
}

// cross-lane fast rotation: partner column at same slot in XOR-partner lane.
template <int CTRL>
__device__ __forceinline__ void xrot(v2f (&a)[8], float& na,
                                     float& d, float& id, bool top) {
  v2f oth[8];
#pragma unroll
  for (int i = 0; i < 8; ++i) oth[i] = dpp2<CTRL>(a[i]);
  float on = dppf<CTRL>(na);
  float od = dppf<CTRL>(d);
  float al = top ? na : on, be = top ? on : na;
  v2f g0 = bc2(0.f), g1 = bc2(0.f);
#pragma unroll
  for (int i = 0; i < 4; ++i) {
    g0 = pkfma(a[i], oth[i], g0);
    g1 = pkfma(a[i + 4], oth[i + 4], g1);
  }
  v2f g = g0 + g1;
  float ga = (d * od) * (g.x + g.y);
  float w = be - al;
  float v = ga + ga;
  float h = fsqrt_fast(fmaf(w, w, v * v));
  float t = v * frcp_fast(w + copysignf(h, w));
  t = (ga == 0.0f) ? 0.0f : t;
  float p = fmaf(t, t, 1.0f);
  float cc = frsq_fast(p);
  float icc = p * cc;
  float tg = t * ga;
  v2f coef = bc2((top ? -t : t) * (od * id));
#pragma unroll
  for (int i = 0; i < 8; ++i) a[i] = pkfma(coef, oth[i], a[i]);
  na += top ? -tg : tg;
  d *= cc; id *= icc;
}

// config-transition move of one slot's column+norm+scales (XOR within quad)
template <int CTRL>
__device__ __forceinline__ void tmov(v2f (&a)[8], float& na,
                                     float& d, float& id) {
#pragma unroll
  for (int i = 0; i < 8; ++i) a[i] = dpp2<CTRL>(a[i]);
  na = dppf<CTRL>(na);
  d = dppf<CTRL>(d);
  id = dppf<CTRL>(id);
}

// ---------------- SVD features + det + trace ----------------
__global__ __launch_bounds__(256) void k_svd(const float* __restrict__ Q,
                                             const float* __restrict__ K,
                                             const float* __restrict__ T,
                                             const float* __restrict__ detT,
                                             float* __restrict__ Sign) {
  int gtid = blockIdx.x * 256 + threadIdx.x;
  int gid = gtid >> 2;          // matrix id, < 131072
  int l = threadIdx.x & 3;      // quad lane = group id
  int k = gid & 15, m = (gid >> 4) & 63, n = (gid >> 10) & 63, b = gid >> 16;
  const float* qrow = Q + (b * 64 + n) * 16;
  const float* krow = K + (b * 64 + m) * 16;

  float qv[16];
#pragma unroll
  for (int i = 0; i < 16; ++i) qv[i] = qrow[i];

  float trace = 0.f, pq = 1.f, pk = 1.f;
#pragma unroll
  for (int i = 0; i < 16; ++i) {
    float kv = krow[i];
    pq *= qv[i]; pk *= kv;
    trace += qv[i] * kv * T[i * 272 + k];   // T[i,i,k]
  }
  float det = pq * pk * detT[k];

  // init in slope-0 config: slot s holds col (x=s, y=l), col index 4s+l
  v2f c0[8], c1[8], c2[8], c3[8];
  float nn0, nn1, nn2, nn3;
  {
    int j0 = l, j1 = 4 + l, j2 = 8 + l, j3 = 12 + l;
    float k0 = krow[j0], k1 = krow[j1], k2 = krow[j2], k3 = krow[j3];
#pragma unroll
    for (int i = 0; i < 8; ++i) {
      float qa = qv[2 * i], qb = qv[2 * i + 1];
      int ra = (2 * i) * 256, rb = (2 * i + 1) * 256;
      c0[i].x = qa * T[ra + j0 * 16 + k] * k0; c0[i].y = qb * T[rb + j0 * 16 + k] * k0;
      c1[i].x = qa * T[ra + j1 * 16 + k] * k1; c1[i].y = qb * T[rb + j1 * 16 + k] * k1;
      c2[i].x = qa * T[ra + j2 * 16 + k] * k2; c2[i].y = qb * T[rb + j2 * 16 + k] * k2;
      c3[i].x = qa * T[ra + j3 * 16 + k] * k3; c3[i].y = qb * T[rb + j3 * 16 + k] * k3;
    }
    v2f a0 = bc2(0.f), a1 = bc2(0.f), a2 = bc2(0.f), a3 = bc2(0.f);
#pragma unroll
    for (int i = 0; i < 8; ++i) {
      a0 = pkfma(c0[i], c0[i], a0);
      a1 = pkfma(c1[i], c1[i], a1);
      a2 = pkfma(c2[i], c2[i], a2);
      a3 = pkfma(c3[i], c3[i], a3);
    }
    nn0 = a0.x + a0.y; nn1 = a1.x + a1.y; nn2 = a2.x + a2.y; nn3 = a3.x + a3.y;
  }
  float d0 = 1.f, d1 = 1.f, d2 = 1.f, d3 = 1.f;
  float i0 = 1.f, i1 = 1.f, i2 = 1.f, i3 = 1.f;

  bool r1 = (l & 1) == 0;   // top role for delta=1
  bool r2 = (l & 2) == 0;   // top role for delta=2 and delta=3

#define INTRA6() { rot2(c0,c1,nn0,nn1,d0,i0,d1,i1); rot2(c2,c3,nn2,nn3,d2,i2,d3,i3); \
                   rot2(c0,c2,nn0,nn2,d0,i0,d2,i2); rot2(c1,c3,nn1,nn3,d1,i1,d3,i3); \
                   rot2(c0,c3,nn0,nn3,d0,i0,d3,i3); rot2(c1,c2,nn1,nn2,d1,i1,d2,i2); }

  for (int sw = 0; sw < SWEEPS; ++sw) {
    // cross-lane phases (same-x pairs), done in slope-0 layout
    xrot<0xB1>(c0, nn0, d0, i0, r1); xrot<0xB1>(c1, nn1, d1, i1, r1);
    xrot<0xB1>(c2, nn2, d2, i2, r1); xrot<0xB1>(c3, nn3, d3, i3, r1);
    xrot<0x4E>(c0, nn0, d0, i0, r2); xrot<0x4E>(c1, nn1, d1, i1, r2);
    xrot<0x4E>(c2, nn2, d2, i2, r2); xrot<0x4E>(c3, nn3, d3, i3, r2);
    xrot<0x1B>(c0, nn0, d0, i0, r2); xrot<0x1B>(c1, nn1, d1, i1, r2);
    xrot<0x1B>(c2, nn2, d2, i2, r2); xrot<0x1B>(c3, nn3, d3, i3, r2);

    INTRA6();                                   // slope 0
    tmov<0xB1>(c1, nn1, d1, i1); tmov<0x4E>(c2, nn2, d2, i2); tmov<0x1B>(c3, nn3, d3, i3);
    INTRA6();                                   // slope 1
    tmov<0x1B>(c1, nn1, d1, i1); tmov<0xB1>(c2, nn2, d2, i2); tmov<0x4E>(c3, nn3, d3, i3);
    INTRA6();                                   // slope 2
    tmov<0xB1>(c1, nn1, d1, i1); tmov<0x4E>(c2, nn2, d2, i2); tmov<0x1B>(c3, nn3, d3, i3);
    INTRA6();                                   // slope 3
    tmov<0x1B>(c1, nn1, d1, i1); tmov<0xB1>(c2, nn2, d2, i2); tmov<0x4E>(c3, nn3, d3, i3);

    // per-sweep rescale: fold scales into columns (bounds dynamic range)
    {
      v2f s0 = bc2(d0), s1 = bc2(d1), s2 = bc2(d2), s3 = bc2(d3);
#pragma unroll
      for (int i = 0; i < 8; ++i) {
        c0[i] *= s0; c1[i] *= s1; c2[i] *= s2; c3[i] *= s3;
      }
    }
    d0 = d1 = d2 = d3 = 1.f;
    i0 = i1 = i2 = i3 = 1.f;
  }
#undef INTRA6

  // exact final norms, reduce across the quad
  v2f a0 = bc2(0.f), a1 = bc2(0.f), a2 = bc2(0.f), a3 = bc2(0.f);
#pragma unroll
  for (int i = 0; i < 8; ++i) {
    a0 = pkfma(c0[i], c0[i], a0);
    a1 = pkfma(c1[i], c1[i], a1);
    a2 = pkfma(c2[i], c2[i], a2);
    a3 = pkfma(c3[i], c3[i], a3);
  }
  float s0 = fsqrt_fast(a0.x + a0.y), s1 = fsqrt_fast(a1.x + a1.y);
  float s2 = fsqrt_fast(a2.x + a2.y), s3 = fsqrt_fast(a3.x + a3.y);
  float lmin = fminf(fminf(s0, s1), fminf(s2, s3));
  float lmax = fmaxf(fmaxf(s0, s1), fmaxf(s2, s3));
  float lsum = __logf(s0 + EPSF) + __logf(s1 + EPSF) +
               __logf(s2 + EPSF) + __logf(s3 + EPSF);
  lmin = fminf(lmin, dppf<0xB1>(lmin));
  lmax = fmaxf(lmax, dppf<0xB1>(lmax));
  lsum += dppf<0xB1>(lsum);
  lmin = fminf(lmin, dppf<0x4E>(lmin));
  lmax = fmaxf(lmax, dppf<0x4E>(lmax));
  lsum += dppf<0x4E>(lsum);
  if (l == 0) {
    float* sp = Sign + (((b * 64 + n) * 64 + m) * 6) * 16 + k;
    sp[0]  = det;
    sp[16] = trace;
    sp[32] = lsum;
    sp[48] = lmin;
    sp[64] = lmax;
  }
}

// ---------------- rho: repeated squaring, quad_perm broadcast, packed ----------------
template <int SRCL>
__device__ __forceinline__ void rho_quarter(v2f (&a)[4][8], v2f (&acc)[4][8]) {
  constexpr int CTRL = SRCL | (SRCL << 2) | (SRCL << 4) | (SRCL << 6);  // quad bcast
#pragma unroll
  for (int c = 0; c < 4; ++c) {        // global column kk = SRCL*4 + c
    v2f colk[8];
#pragma unroll
    for (int i = 0; i < 8; ++i) colk[i] = dpp2<CTRL>(a[c][i]);  // A[.][kk]
    constexpr int R = SRCL * 4;        // row base (c added below, both static)
#pragma unroll
    for (int jj = 0; jj < 4; ++jj) {
      int r = R + c;                   // static after unroll
      float f = (r & 1) ? a[jj][r >> 1].y : a[jj][r >> 1].x;  // A[kk][own col jj]
      v2f fv = bc2(f);
#pragma unroll
      for (int i = 0; i < 8; ++i) acc[jj][i] = pkfma(colk[i], fv, acc[jj][i]);
    }
  }
}

__global__ __launch_bounds__(128) void k_rho(const float* __restrict__ Q,
                                             const float* __restrict__ K,
                                             const float* __restrict__ T,
                                             float* __restrict__ Sign) {
  int gtid = blockIdx.x * 128 + threadIdx.x;
  int gid = gtid >> 2;              // matrix id, < 131072
  int l = threadIdx.x & 3;
  int k = gid & 15, m = (gid >> 4) & 63, n = (gid >> 10) & 63, b = gid >> 16;
  const float* qrow = Q + (b * 64 + n) * 16;
  const float* krow = K + (b * 64 + m) * 16;

  v2f a[4][8];
#pragma unroll
  for (int jj = 0; jj < 4; ++jj) {
    int j = 4 * l + jj;
    float w = qrow[j] * krow[j];
#pragma unroll
    for (int i = 0; i < 8; ++i) {
      a[jj][i].x = T[(2 * i) * 256 + j * 16 + k] * w;
      a[jj][i].y = T[(2 * i + 1) * 256 + j * 16 + k] * w;
    }
  }

  // L = sum_{i<J} log(ss_i)*2^-(i+1) + log(ss_J)*2^-J (geometric tail)
  float L = 0.0f, wgt = 0.5f;
  for (int it = 0; it <= RHO_J; ++it) {
    v2f p0 = bc2(0.f), p1 = bc2(0.f), p2 = bc2(0.f), p3 = bc2(0.f);
#pragma unroll
    for (int i = 0; i < 8; ++i) {
      p0 = pkfma(a[0][i], a[0][i], p0);
      p1 = pkfma(a[1][i], a[1][i], p1);
      p2 = pkfma(a[2][i], a[2][i], p2);
      p3 = pkfma(a[3][i], a[3][i], p3);
    }
    v2f ps = (p0 + p1) + (p2 + p3);
    float ss = ps.x + ps.y;
    ss += dppf<0xB1>(ss);
    ss += dppf<0x4E>(ss);
    float w2 = (it == RHO_J) ? (wgt + wgt) : wgt;
    L = fmaf(__logf(ss), w2, L);
    wgt *= 0.5f;
    if (it == RHO_J) break;
    float s = (ss > 0.0f) ? frcp_fast(ss) : 0.0f;

    v2f acc[4][8];
#pragma unroll
    for (int jj = 0; jj < 4; ++jj)
#pragma unroll
      for (int i = 0; i < 8; ++i) acc[jj][i] = bc2(0.f);

    rho_quarter<0>(a, acc);
    rho_quarter<1>(a, acc);
    rho_quarter<2>(a, acc);
    rho_quarter<3>(a, acc);

    v2f sv = bc2(s);
#pragma unroll
    for (int jj = 0; jj < 4; ++jj)
#pragma unroll
      for (int i = 0; i < 8; ++i) a[jj][i] = acc[jj][i] * sv;
  }
  float rho = __expf(L);
  if (l == 0) Sign[(((b * 64 + n) * 64 + m) * 6 + 5) * 16 + k] = rho;
}

// ---------------- out[b,n,v] = sum_{m,s,k} Sign * V ----------------
__global__ __launch_bounds__(256) void k_out(const float* __restrict__ Sign,
                                             const float* __restrict__ V,
                                             float* __restrict__ out) {
  __shared__ float red[256];
  int bn = blockIdx.x;              // 0..127
  int b = bn >> 6;
  int t = threadIdx.x;
  int v = t & 15, mc = t >> 4;      // m in [mc*4, mc*4+4)
  const float* sp = Sign + bn * 6144;
  const float* vp = V + b * 98304;
  float acc = 0.f;
  for (int mm = 0; mm < 4; ++mm) {
    int m = mc * 4 + mm;
    const float* sr = sp + m * 96;
    const float* vr = vp + m * 1536 + v;
#pragma unroll
    for (int sk = 0; sk < 96; ++sk) acc = fmaf(sr[sk], vr[sk * 16], acc);
  }
  red[t] = acc;
  __syncthreads();
  for (int off = 128; off >= 16; off >>= 1) {
    if (t < off) red[t] += red[t + off];
    __syncthreads();
  }
  if (t < 16) out[bn * 16 + t] = red[t];
}

extern "C" void kernel_launch(void* const* d_in, const int* in_sizes, int n_in,
                              void* d_out, int out_size, void* d_ws, size_t ws_size,
                              hipStream_t stream) {
  const float* X  = (const float*)d_in[0];
  const float* Wk = (const float*)d_in[1];
  const float* Wq = (const float*)d_in[2];
  const float* T  = (const float*)d_in[3];
  const float* Wv = (const float*)d_in[4];
  float* out = (float*)d_out;
  float* ws = (float*)d_ws;

  float* Q    = ws + WS_Q;
  float* K    = ws + WS_K;
  float* detT = ws + WS_DETT;
  float* V    = ws + WS_V;
  float* Sign = ws + WS_SIGN;

  hipLaunchKernelGGL(k_setup, dim3(777),  dim3(256), 0, stream,
                     X, Wk, Wq, T, Wv, Q, K, detT, V);
  hipLaunchKernelGGL(k_svd,   dim3(2048), dim3(256), 0, stream, Q, K, T, detT, Sign);
  hipLaunchKernelGGL(k_rho,   dim3(4096), dim3(128), 0, stream, Q, K, T, Sign);
  hipLaunchKernelGGL(k_out,   dim3(128),  dim3(256), 0, stream, Sign, V, out);
}

// Round 10
// 387.548 us; speedup vs baseline: 3.8484x; 1.1446x over previous
//
#include <hip/hip_runtime.h>
#include <math.h>

// Problem: B=2, N=64, D=16.
// C_{b,n,m,k} = diag(Q_n) T_k diag(K_m), 131072 16x16 matrices.
// det/trace closed-form; sigma via one-sided block-Jacobi (4 lanes x 4 cols,
// GF(4) spread schedule, comm = 1-inst mov_dpp, fast scaled rotations);
// rho via normalized repeated squaring + geometric tail.
// R9: packed FP32 (v_pk_fma_f32) throughout the hot loops.
// R10: SWEEPS 6->5 (R3 evidence: absmax ~5 at 5 sweeps), RHO_J 10->8
// (tail-corrected; J=14/12/10 all gave identical absmax).

#define EPSF 1e-6f
#define SWEEPS 5
#define RHO_J 8

// workspace float offsets
#define WS_Q    0         // [2][64][16]            = 2048
#define WS_K    2048      // [2][64][16]            = 2048
#define WS_DETT 4096      // [16]
#define WS_V    4352      // [2][64][6][16][16]     = 196608
#define WS_SIGN 200960    // [2][64][64][6][16]     = 786432

typedef float v2f __attribute__((ext_vector_type(2)));

// quad_perm DPP: ctrl = p0|p1<<2|p2<<4|p3<<6; XOR masks: 1->0xB1, 2->0x4E, 3->0x1B
template <int CTRL>
__device__ __forceinline__ float dppf(float v) {
  return __int_as_float(__builtin_amdgcn_mov_dpp(__float_as_int(v), CTRL, 0xF, 0xF, true));
}
template <int CTRL>
__device__ __forceinline__ v2f dpp2(v2f v) {
  v2f r;
  r.x = dppf<CTRL>(v.x);
  r.y = dppf<CTRL>(v.y);
  return r;
}
__device__ __forceinline__ v2f pkfma(v2f a, v2f b, v2f c) {
  return __builtin_elementwise_fma(a, b, c);
}
__device__ __forceinline__ v2f bc2(float s) { v2f r; r.x = s; r.y = s; return r; }
__device__ __forceinline__ float fsqrt_fast(float x) { return __builtin_amdgcn_sqrtf(x); }
__device__ __forceinline__ float frcp_fast(float x)  { return __builtin_amdgcn_rcpf(x); }
__device__ __forceinline__ float frsq_fast(float x)  { return __builtin_amdgcn_rsqf(x); }

// ---------------- fused setup: V (768 blocks) | QK (8 blocks) | detT (1 block) ----------------
__global__ __launch_bounds__(256) void k_setup(const float* __restrict__ X,
                                               const float* __restrict__ Wk,
                                               const float* __restrict__ Wq,
                                               const float* __restrict__ T,
                                               const float* __restrict__ Wv,
                                               float* __restrict__ Q,
                                               float* __restrict__ Kout,
                                               float* __restrict__ detT,
                                               float* __restrict__ V) {
  int blk = blockIdx.x;
  if (blk < 768) {
    int t = blk * 256 + threadIdx.x;          // 196608 threads for V
    int bm = t / 1536; int rem = t - bm * 1536;
    int s = rem >> 8; int kk = (rem >> 4) & 15; int v = rem & 15;
    const float* x = X + bm * 16;
    float acc = 0.f;
#pragma unroll
    for (int d = 0; d < 16; ++d) acc += x[d] * Wv[((d * 6 + s) * 16 + kk) * 16 + v];
    V[t] = acc;
  } else if (blk < 776) {
    int t = (blk - 768) * 256 + threadIdx.x;  // 2048 threads for Q,K
    int i = t & 15, bn = t >> 4;
    const float* x = X + bn * 16;
    float q = 0.f, kk = 0.f;
#pragma unroll
    for (int d = 0; d < 16; ++d) {
      float xv = x[d];
      q  += xv * Wq[d * 16 + i];
      kk += xv * Wk[d * 16 + i];
    }
    Q[t] = q; Kout[t] = kk;
  } else {
    // det(T_k) via LU with partial pivoting
    __shared__ float A[16][16][16];  // [k][i][j]
    for (int idx = threadIdx.x; idx < 4096; idx += 256) {
      int i = idx >> 8, j = (idx >> 4) & 15, kk = idx & 15;
      A[kk][i][j] = T[idx];          // T[i,j,k] at i*256+j*16+k
    }
    __syncthreads();
    int k = threadIdx.x;
    if (k < 16) {
      float det = 1.0f;
      for (int c = 0; c < 16; ++c) {
        int p = c; float mx = fabsf(A[k][c][c]);
        for (int r = c + 1; r < 16; ++r) {
          float v = fabsf(A[k][r][c]);
          if (v > mx) { mx = v; p = r; }
        }
        if (mx == 0.0f) { det = 0.0f; break; }
        if (p != c) {
          det = -det;
          for (int cc = c; cc < 16; ++cc) {
            float tmp = A[k][c][cc]; A[k][c][cc] = A[k][p][cc]; A[k][p][cc] = tmp;
          }
        }
        float piv = A[k][c][c];
        det *= piv;
        float inv = 1.0f / piv;
        for (int r = c + 1; r < 16; ++r) {
          float f = A[k][r][c] * inv;
          for (int cc = c + 1; cc < 16; ++cc) A[k][r][cc] -= f * A[k][c][cc];
        }
      }
      detT[k] = det;
    }
  }
}

// ---------------- fast scaled Jacobi helpers (packed) ----------------
// Actual column = d * stored column. a' = a - t*(db/da)*b, b' = b + t*(da/db)*a,
// da*=c, db*=c. Norms na,nb are TRUE squared norms (Rutishauser-carried).

__device__ __forceinline__ void rot2(v2f (&a)[8], v2f (&b)[8],
                                     float& na, float& nb,
                                     float& da, float& ida,
                                     float& db, float& idb) {
  v2f g0 = bc2(0.f), g1 = bc2(0.f);
#pragma unroll
  for (int i = 0; i < 4; ++i) {
    g0 = pkfma(a[i], b[i], g0);
    g1 = pkfma(a[i + 4], b[i + 4], g1);
  }
  v2f g = g0 + g1;
  float ga = (da * db) * (g.x + g.y);   // true gamma
  float w = nb - na;
  float v = ga + ga;
  float h = fsqrt_fast(fmaf(w, w, v * v));
  float t = v * frcp_fast(w + copysignf(h, w));
  t = (ga == 0.0f) ? 0.0f : t;
  float p = fmaf(t, t, 1.0f);
  float cc = frsq_fast(p);
  float icc = p * cc;                 // 1/cc
  float tg = t * ga;
  v2f t1 = bc2(-t * (db * ida));
  v2f t2 = bc2( t * (da * idb));
#pragma unroll
  for (int i = 0; i < 8; ++i) {
    v2f ai = a[i];
    a[i] = pkfma(t1, b[i], ai);
    b[i] = pkfma(t2, ai, b[i]);
  }
  na -= tg; nb += tg;
  da *= cc; db *= cc; ida *= icc; idb *= icc;
}

// cross-lane fast rotation: partner column at same slot in XOR-partner lane.
template <int CTRL>
__device__ __forceinline__ void xrot(v2f (&a)[8], float& na,
                                     float& d, float& id, bool top) {
  v2f oth[8];
#pragma unroll
  for (int i = 0; i < 8; ++i) oth[i] = dpp2<CTRL>(a[i]);
  float on = dppf<CTRL>(na);
  float od = dppf<CTRL>(d);
  float al = top ? na : on, be = top ? on : na;
  v2f g0 = bc2(0.f), g1 = bc2(0.f);
#pragma unroll
  for (int i = 0; i < 4; ++i) {
    g0 = pkfma(a[i], oth[i], g0);
    g1 = pkfma(a[i + 4], oth[i + 4], g1);
  }
  v2f g = g0 + g1;
  float ga = (d * od) * (g.x + g.y);
  float w = be - al;
  float v = ga + ga;
  float h = fsqrt_fast(fmaf(w, w, v * v));
  float t = v * frcp_fast(w + copysignf(h, w));
  t = (ga == 0.0f) ? 0.0f : t;
  float p = fmaf(t, t, 1.0f);
  float cc = frsq_fast(p);
  float icc = p * cc;
  float tg = t * ga;
  v2f coef = bc2((top ? -t : t) * (od * id));
#pragma unroll
  for (int i = 0; i < 8; ++i) a[i] = pkfma(coef, oth[i], a[i]);
  na += top ? -tg : tg;
  d *= cc; id *= icc;
}

// config-transition move of one slot's column+norm+scales (XOR within quad)
template <int CTRL>
__device__ __forceinline__ void tmov(v2f (&a)[8], float& na,
                                     float& d, float& id) {
#pragma unroll
  for (int i = 0; i < 8; ++i) a[i] = dpp2<CTRL>(a[i]);
  na = dppf<CTRL>(na);
  d = dppf<CTRL>(d);
  id = dppf<CTRL>(id);
}

// ---------------- SVD features + det + trace ----------------
__global__ __launch_bounds__(256) void k_svd(const float* __restrict__ Q,
                                             const float* __restrict__ K,
                                             const float* __restrict__ T,
                                             const float* __restrict__ detT,
                                             float* __restrict__ Sign) {
  int gtid = blockIdx.x * 256 + threadIdx.x;
  int gid = gtid >> 2;          // matrix id, < 131072
  int l = threadIdx.x & 3;      // quad lane = group id
  int k = gid & 15, m = (gid >> 4) & 63, n = (gid >> 10) & 63, b = gid >> 16;
  const float* qrow = Q + (b * 64 + n) * 16;
  const float* krow = K + (b * 64 + m) * 16;

  float qv[16];
#pragma unroll
  for (int i = 0; i < 16; ++i) qv[i] = qrow[i];

  float trace = 0.f, pq = 1.f, pk = 1.f;
#pragma unroll
  for (int i = 0; i < 16; ++i) {
    float kv = krow[i];
    pq *= qv[i]; pk *= kv;
    trace += qv[i] * kv * T[i * 272 + k];   // T[i,i,k]
  }
  float det = pq * pk * detT[k];

  // init in slope-0 config: slot s holds col (x=s, y=l), col index 4s+l
  v2f c0[8], c1[8], c2[8], c3[8];
  float nn0, nn1, nn2, nn3;
  {
    int j0 = l, j1 = 4 + l, j2 = 8 + l, j3 = 12 + l;
    float k0 = krow[j0], k1 = krow[j1], k2 = krow[j2], k3 = krow[j3];
#pragma unroll
    for (int i = 0; i < 8; ++i) {
      float qa = qv[2 * i], qb = qv[2 * i + 1];
      int ra = (2 * i) * 256, rb = (2 * i + 1) * 256;
      c0[i].x = qa * T[ra + j0 * 16 + k] * k0; c0[i].y = qb * T[rb + j0 * 16 + k] * k0;
      c1[i].x = qa * T[ra + j1 * 16 + k] * k1; c1[i].y = qb * T[rb + j1 * 16 + k] * k1;
      c2[i].x = qa * T[ra + j2 * 16 + k] * k2; c2[i].y = qb * T[rb + j2 * 16 + k] * k2;
      c3[i].x = qa * T[ra + j3 * 16 + k] * k3; c3[i].y = qb * T[rb + j3 * 16 + k] * k3;
    }
    v2f a0 = bc2(0.f), a1 = bc2(0.f), a2 = bc2(0.f), a3 = bc2(0.f);
#pragma unroll
    for (int i = 0; i < 8; ++i) {
      a0 = pkfma(c0[i], c0[i], a0);
      a1 = pkfma(c1[i], c1[i], a1);
      a2 = pkfma(c2[i], c2[i], a2);
      a3 = pkfma(c3[i], c3[i], a3);
    }
    nn0 = a0.x + a0.y; nn1 = a1.x + a1.y; nn2 = a2.x + a2.y; nn3 = a3.x + a3.y;
  }
  float d0 = 1.f, d1 = 1.f, d2 = 1.f, d3 = 1.f;
  float i0 = 1.f, i1 = 1.f, i2 = 1.f, i3 = 1.f;

  bool r1 = (l & 1) == 0;   // top role for delta=1
  bool r2 = (l & 2) == 0;   // top role for delta=2 and delta=3

#define INTRA6() { rot2(c0,c1,nn0,nn1,d0,i0,d1,i1); rot2(c2,c3,nn2,nn3,d2,i2,d3,i3); \
                   rot2(c0,c2,nn0,nn2,d0,i0,d2,i2); rot2(c1,c3,nn1,nn3,d1,i1,d3,i3); \
                   rot2(c0,c3,nn0,nn3,d0,i0,d3,i3); rot2(c1,c2,nn1,nn2,d1,i1,d2,i2); }

  for (int sw = 0; sw < SWEEPS; ++sw) {
    // cross-lane phases (same-x pairs), done in slope-0 layout
    xrot<0xB1>(c0, nn0, d0, i0, r1); xrot<0xB1>(c1, nn1, d1, i1, r1);
    xrot<0xB1>(c2, nn2, d2, i2, r1); xrot<0xB1>(c3, nn3, d3, i3, r1);
    xrot<0x4E>(c0, nn0, d0, i0, r2); xrot<0x4E>(c1, nn1, d1, i1, r2);
    xrot<0x4E>(c2, nn2, d2, i2, r2); xrot<0x4E>(c3, nn3, d3, i3, r2);
    xrot<0x1B>(c0, nn0, d0, i0, r2); xrot<0x1B>(c1, nn1, d1, i1, r2);
    xrot<0x1B>(c2, nn2, d2, i2, r2); xrot<0x1B>(c3, nn3, d3, i3, r2);

    INTRA6();                                   // slope 0
    tmov<0xB1>(c1, nn1, d1, i1); tmov<0x4E>(c2, nn2, d2, i2); tmov<0x1B>(c3, nn3, d3, i3);
    INTRA6();                                   // slope 1
    tmov<0x1B>(c1, nn1, d1, i1); tmov<0xB1>(c2, nn2, d2, i2); tmov<0x4E>(c3, nn3, d3, i3);
    INTRA6();                                   // slope 2
    tmov<0xB1>(c1, nn1, d1, i1); tmov<0x4E>(c2, nn2, d2, i2); tmov<0x1B>(c3, nn3, d3, i3);
    INTRA6();                                   // slope 3
    tmov<0x1B>(c1, nn1, d1, i1); tmov<0xB1>(c2, nn2, d2, i2); tmov<0x4E>(c3, nn3, d3, i3);

    // per-sweep rescale: fold scales into columns (bounds dynamic range)
    {
      v2f s0 = bc2(d0), s1 = bc2(d1), s2 = bc2(d2), s3 = bc2(d3);
#pragma unroll
      for (int i = 0; i < 8; ++i) {
        c0[i] *= s0; c1[i] *= s1; c2[i] *= s2; c3[i] *= s3;
      }
    }
    d0 = d1 = d2 = d3 = 1.f;
    i0 = i1 = i2 = i3 = 1.f;
  }
#undef INTRA6

  // exact final norms, reduce across the quad
  v2f a0 = bc2(0.f), a1 = bc2(0.f), a2 = bc2(0.f), a3 = bc2(0.f);
#pragma unroll
  for (int i = 0; i < 8; ++i) {
    a0 = pkfma(c0[i], c0[i], a0);
    a1 = pkfma(c1[i], c1[i], a1);
    a2 = pkfma(c2[i], c2[i], a2);
    a3 = pkfma(c3[i], c3[i], a3);
  }
  float s0 = fsqrt_fast(a0.x + a0.y), s1 = fsqrt_fast(a1.x + a1.y);
  float s2 = fsqrt_fast(a2.x + a2.y), s3 = fsqrt_fast(a3.x + a3.y);
  float lmin = fminf(fminf(s0, s1), fminf(s2, s3));
  float lmax = fmaxf(fmaxf(s0, s1), fmaxf(s2, s3));
  float lsum = __logf(s0 + EPSF) + __logf(s1 + EPSF) +
               __logf(s2 + EPSF) + __logf(s3 + EPSF);
  lmin = fminf(lmin, dppf<0xB1>(lmin));
  lmax = fmaxf(lmax, dppf<0xB1>(lmax));
  lsum += dppf<0xB1>(lsum);
  lmin = fminf(lmin, dppf<0x4E>(lmin));
  lmax = fmaxf(lmax, dppf<0x4E>(lmax));
  lsum += dppf<0x4E>(lsum);
  if (l == 0) {
    float* sp = Sign + (((b * 64 + n) * 64 + m) * 6) * 16 + k;
    sp[0]  = det;
    sp[16] = trace;
    sp[32] = lsum;
    sp[48] = lmin;
    sp[64] = lmax;
  }
}

// ---------------- rho: repeated squaring, quad_perm broadcast, packed ----------------
template <int SRCL>
__device__ __forceinline__ void rho_quarter(v2f (&a)[4][8], v2f (&acc)[4][8]) {
  constexpr int CTRL = SRCL | (SRCL << 2) | (SRCL << 4) | (SRCL << 6);  // quad bcast
#pragma unroll
  for (int c = 0; c < 4; ++c) {        // global column kk = SRCL*4 + c
    v2f colk[8];
#pragma unroll
    for (int i = 0; i < 8; ++i) colk[i] = dpp2<CTRL>(a[c][i]);  // A[.][kk]
    constexpr int R = SRCL * 4;        // row base (c added below, both static)
#pragma unroll
    for (int jj = 0; jj < 4; ++jj) {
      int r = R + c;                   // static after unroll
      float f = (r & 1) ? a[jj][r >> 1].y : a[jj][r >> 1].x;  // A[kk][own col jj]
      v2f fv = bc2(f);
#pragma unroll
      for (int i = 0; i < 8; ++i) acc[jj][i] = pkfma(colk[i], fv, acc[jj][i]);
    }
  }
}

__global__ __launch_bounds__(128) void k_rho(const float* __restrict__ Q,
                                             const float* __restrict__ K,
                                             const float* __restrict__ T,
                                             float* __restrict__ Sign) {
  int gtid = blockIdx.x * 128 + threadIdx.x;
  int gid = gtid >> 2;              // matrix id, < 131072
  int l = threadIdx.x & 3;
  int k = gid & 15, m = (gid >> 4) & 63, n = (gid >> 10) & 63, b = gid >> 16;
  const float* qrow = Q + (b * 64 + n) * 16;
  const float* krow = K + (b * 64 + m) * 16;

  v2f a[4][8];
#pragma unroll
  for (int jj = 0; jj < 4; ++jj) {
    int j = 4 * l + jj;
    float w = qrow[j] * krow[j];
#pragma unroll
    for (int i = 0; i < 8; ++i) {
      a[jj][i].x = T[(2 * i) * 256 + j * 16 + k] * w;
      a[jj][i].y = T[(2 * i + 1) * 256 + j * 16 + k] * w;
    }
  }

  // L = sum_{i<J} log(ss_i)*2^-(i+1) + log(ss_J)*2^-J (geometric tail)
  float L = 0.0f, wgt = 0.5f;
  for (int it = 0; it <= RHO_J; ++it) {
    v2f p0 = bc2(0.f), p1 = bc2(0.f), p2 = bc2(0.f), p3 = bc2(0.f);
#pragma unroll
    for (int i = 0; i < 8; ++i) {
      p0 = pkfma(a[0][i], a[0][i], p0);
      p1 = pkfma(a[1][i], a[1][i], p1);
      p2 = pkfma(a[2][i], a[2][i], p2);
      p3 = pkfma(a[3][i], a[3][i], p3);
    }
    v2f ps = (p0 + p1) + (p2 + p3);
    float ss = ps.x + ps.y;
    ss += dppf<0xB1>(ss);
    ss += dppf<0x4E>(ss);
    float w2 = (it == RHO_J) ? (wgt + wgt) : wgt;
    L = fmaf(__logf(ss), w2, L);
    wgt *= 0.5f;
    if (it == RHO_J) break;
    float s = (ss > 0.0f) ? frcp_fast(ss) : 0.0f;

    v2f acc[4][8];
#pragma unroll
    for (int jj = 0; jj < 4; ++jj)
#pragma unroll
      for (int i = 0; i < 8; ++i) acc[jj][i] = bc2(0.f);

    rho_quarter<0>(a, acc);
    rho_quarter<1>(a, acc);
    rho_quarter<2>(a, acc);
    rho_quarter<3>(a, acc);

    v2f sv = bc2(s);
#pragma unroll
    for (int jj = 0; jj < 4; ++jj)
#pragma unroll
      for (int i = 0; i < 8; ++i) a[jj][i] = acc[jj][i] * sv;
  }
  float rho = __expf(L);
  if (l == 0) Sign[(((b * 64 + n) * 64 + m) * 6 + 5) * 16 + k] = rho;
}

// ---------------- out[b,n,v] = sum_{m,s,k} Sign * V ----------------
__global__ __launch_bounds__(256) void k_out(const float* __restrict__ Sign,
                                             const float* __restrict__ V,
                                             float* __restrict__ out) {
  __shared__ float red[256];
  int bn = blockIdx.x;              // 0..127
  int b = bn >> 6;
  int t = threadIdx.x;
  int v = t & 15, mc = t >> 4;      // m in [mc*4, mc*4+4)
  const float* sp = Sign + bn * 6144;
  const float* vp = V + b * 98304;
  float acc = 0.f;
  for (int mm = 0; mm < 4; ++mm) {
    int m = mc * 4 + mm;
    const float* sr = sp + m * 96;
    const float* vr = vp + m * 1536 + v;
#pragma unroll
    for (int sk = 0; sk < 96; ++sk) acc = fmaf(sr[sk], vr[sk * 16], acc);
  }
  red[t] = acc;
  __syncthreads();
  for (int off = 128; off >= 16; off >>= 1) {
    if (t < off) red[t] += red[t + off];
    __syncthreads();
  }
  if (t < 16) out[bn * 16 + t] = red[t];
}

extern "C" void kernel_launch(void* const* d_in, const int* in_sizes, int n_in,
                              void* d_out, int out_size, void* d_ws, size_t ws_size,
                              hipStream_t stream) {
  const float* X  = (const float*)d_in[0];
  const float* Wk = (const float*)d_in[1];
  const float* Wq = (const float*)d_in[2];
  const float* T  = (const float*)d_in[3];
  const float* Wv = (const float*)d_in[4];
  float* out = (float*)d_out;
  float* ws = (float*)d_ws;

  float* Q    = ws + WS_Q;
  float* K    = ws + WS_K;
  float* detT = ws + WS_DETT;
  float* V    = ws + WS_V;
  float* Sign = ws + WS_SIGN;

  hipLaunchKernelGGL(k_setup, dim3(777),  dim3(256), 0, stream,
                     X, Wk, Wq, T, Wv, Q, K, detT, V);
  hipLaunchKernelGGL(k_svd,   dim3(2048), dim3(256), 0, stream, Q, K, T, detT, Sign);
  hipLaunchKernelGGL(k_rho,   dim3(4096), dim3(128), 0, stream, Q, K, T, Sign);
  hipLaunchKernelGGL(k_out,   dim3(128),  dim3(256), 0, stream, Sign, V, out);
}

// Round 11
// 381.441 us; speedup vs baseline: 3.9100x; 1.0160x over previous
//
#include <hip/hip_runtime.h>
#include <math.h>

// Problem: B=2, N=64, D=16.
// C_{b,n,m,k} = diag(Q_n) T_k diag(K_m), 131072 16x16 matrices.
// det/trace closed-form; sigma via one-sided block-Jacobi (4 lanes x 4 cols,
// GF(4) spread schedule, mov_dpp comm, fast scaled rotations, packed fp32);
// rho via normalized repeated squaring + geometric tail (packed fp32).
// R11: k_svd + k_rho MERGED into k_main (block-range split) so the two
// independent phases overlap on the CUs (no inter-kernel barrier);
// rho first-quarter writes acc directly (no zero-init); svd last-sweep
// rescale folded into final norms.

#define EPSF 1e-6f
#define SWEEPS 5
#define RHO_J 8

// workspace float offsets
#define WS_Q    0         // [2][64][16]            = 2048
#define WS_K    2048      // [2][64][16]            = 2048
#define WS_DETT 4096      // [16]
#define WS_V    4352      // [2][64][6][16][16]     = 196608
#define WS_SIGN 200960    // [2][64][64][6][16]     = 786432

typedef float v2f __attribute__((ext_vector_type(2)));

// quad_perm DPP: ctrl = p0|p1<<2|p2<<4|p3<<6; XOR masks: 1->0xB1, 2->0x4E, 3->0x1B
template <int CTRL>
__device__ __forceinline__ float dppf(float v) {
  return __int_as_float(__builtin_amdgcn_mov_dpp(__float_as_int(v), CTRL, 0xF, 0xF, true));
}
template <int CTRL>
__device__ __forceinline__ v2f dpp2(v2f v) {
  v2f r;
  r.x = dppf<CTRL>(v.x);
  r.y = dppf<CTRL>(v.y);
  return r;
}
__device__ __forceinline__ v2f pkfma(v2f a, v2f b, v2f c) {
  return __builtin_elementwise_fma(a, b, c);
}
__device__ __forceinline__ v2f bc2(float s) { v2f r; r.x = s; r.y = s; return r; }
__device__ __forceinline__ float fsqrt_fast(float x) { return __builtin_amdgcn_sqrtf(x); }
__device__ __forceinline__ float frcp_fast(float x)  { return __builtin_amdgcn_rcpf(x); }
__device__ __forceinline__ float frsq_fast(float x)  { return __builtin_amdgcn_rsqf(x); }

// ---------------- fused setup: V (768 blocks) | QK (8 blocks) | detT (1 block) ----------------
__global__ __launch_bounds__(256) void k_setup(const float* __restrict__ X,
                                               const float* __restrict__ Wk,
                                               const float* __restrict__ Wq,
                                               const float* __restrict__ T,
                                               const float* __restrict__ Wv,
                                               float* __restrict__ Q,
                                               float* __restrict__ Kout,
                                               float* __restrict__ detT,
                                               float* __restrict__ V) {
  int blk = blockIdx.x;
  if (blk < 768) {
    int t = blk * 256 + threadIdx.x;          // 196608 threads for V
    int bm = t / 1536; int rem = t - bm * 1536;
    int s = rem >> 8; int kk = (rem >> 4) & 15; int v = rem & 15;
    const float* x = X + bm * 16;
    float acc = 0.f;
#pragma unroll
    for (int d = 0; d < 16; ++d) acc += x[d] * Wv[((d * 6 + s) * 16 + kk) * 16 + v];
    V[t] = acc;
  } else if (blk < 776) {
    int t = (blk - 768) * 256 + threadIdx.x;  // 2048 threads for Q,K
    int i = t & 15, bn = t >> 4;
    const float* x = X + bn * 16;
    float q = 0.f, kk = 0.f;
#pragma unroll
    for (int d = 0; d < 16; ++d) {
      float xv = x[d];
      q  += xv * Wq[d * 16 + i];
      kk += xv * Wk[d * 16 + i];
    }
    Q[t] = q; Kout[t] = kk;
  } else {
    // det(T_k) via LU with partial pivoting
    __shared__ float A[16][16][16];  // [k][i][j]
    for (int idx = threadIdx.x; idx < 4096; idx += 256) {
      int i = idx >> 8, j = (idx >> 4) & 15, kk = idx & 15;
      A[kk][i][j] = T[idx];          // T[i,j,k] at i*256+j*16+k
    }
    __syncthreads();
    int k = threadIdx.x;
    if (k < 16) {
      float det = 1.0f;
      for (int c = 0; c < 16; ++c) {
        int p = c; float mx = fabsf(A[k][c][c]);
        for (int r = c + 1; r < 16; ++r) {
          float v = fabsf(A[k][r][c]);
          if (v > mx) { mx = v; p = r; }
        }
        if (mx == 0.0f) { det = 0.0f; break; }
        if (p != c) {
          det = -det;
          for (int cc = c; cc < 16; ++cc) {
            float tmp = A[k][c][cc]; A[k][c][cc] = A[k][p][cc]; A[k][p][cc] = tmp;
          }
        }
        float piv = A[k][c][c];
        det *= piv;
        float inv = 1.0f / piv;
        for (int r = c + 1; r < 16; ++r) {
          float f = A[k][r][c] * inv;
          for (int cc = c + 1; cc < 16; ++cc) A[k][r][cc] -= f * A[k][c][cc];
        }
      }
      detT[k] = det;
    }
  }
}

// ---------------- fast scaled Jacobi helpers (packed) ----------------
// Actual column = d * stored column. a' = a - t*(db/da)*b, b' = b + t*(da/db)*a,
// da*=c, db*=c. Norms na,nb are TRUE squared norms (Rutishauser-carried).

__device__ __forceinline__ void rot2(v2f (&a)[8], v2f (&b)[8],
                                     float& na, float& nb,
                                     float& da, float& ida,
                                     float& db, float& idb) {
  v2f g0 = bc2(0.f), g1 = bc2(0.f);
#pragma unroll
  for (int i = 0; i < 4; ++i) {
    g0 = pkfma(a[i], b[i], g0);
    g1 = pkfma(a[i + 4], b[i + 4], g1);
  }
  v2f g = g0 + g1;
  float ga = (da * db) * (g.x + g.y);   // true gamma
  float w = nb - na;
  float v = ga + ga;
  float h = fsqrt_fast(fmaf(w, w, v * v));
  float t = v * frcp_fast(w + copysignf(h, w));
  t = (ga == 0.0f) ? 0.0f : t;
  float p = fmaf(t, t, 1.0f);
  float cc = frsq_fast(p);
  float icc = p * cc;                 // 1/cc
  float tg = t * ga;
  v2f t1 = bc2(-t * (db * ida));
  v2f t2 = bc2( t * (da * idb));
#pragma unroll
  for (int i = 0; i < 8; ++i) {
    v2f ai = a[i];
    a[i] = pkfma(t1, b[i], ai);
    b[i] = pkfma(t2, ai, b[i]);
  }
  na -= tg; nb += tg;
  da *= cc; db *= cc; ida *= icc; idb *= icc;
}

// cross-lane fast rotation: partner column at same slot in XOR-partner lane.
template <int CTRL>
__device__ __forceinline__ void xrot(v2f (&a)[8], float& na,
                                     float& d, float& id, bool top) {
  v2f oth[8];
#pragma unroll
  for (int i = 0; i < 8; ++i) oth[i] = dpp2<CTRL>(a[i]);
  float on = dppf<CTRL>(na);
  float od = dppf<CTRL>(d);
  float al = top ? na : on, be = top ? on : na;
  v2f g0 = bc2(0.f), g1 = bc2(0.f);
#pragma unroll
  for (int i = 0; i < 4; ++i) {
    g0 = pkfma(a[i], oth[i], g0);
    g1 = pkfma(a[i + 4], oth[i + 4], g1);
  }
  v2f g = g0 + g1;
  float ga = (d * od) * (g.x + g.y);
  float w = be - al;
  float v = ga + ga;
  float h = fsqrt_fast(fmaf(w, w, v * v));
  float t = v * frcp_fast(w + copysignf(h, w));
  t = (ga == 0.0f) ? 0.0f : t;
  float p = fmaf(t, t, 1.0f);
  float cc = frsq_fast(p);
  float icc = p * cc;
  float tg = t * ga;
  v2f coef = bc2((top ? -t : t) * (od * id));
#pragma unroll
  for (int i = 0; i < 8; ++i) a[i] = pkfma(coef, oth[i], a[i]);
  na += top ? -tg : tg;
  d *= cc; id *= icc;
}

// config-transition move of one slot's column+norm+scales (XOR within quad)
template <int CTRL>
__device__ __forceinline__ void tmov(v2f (&a)[8], float& na,
                                     float& d, float& id) {
#pragma unroll
  for (int i = 0; i < 8; ++i) a[i] = dpp2<CTRL>(a[i]);
  na = dppf<CTRL>(na);
  d = dppf<CTRL>(d);
  id = dppf<CTRL>(id);
}

// ---------------- SVD body: features det/trace/rank/smin/smax ----------------
__device__ __forceinline__ void svd_body(int blk, const float* __restrict__ Q,
                                         const float* __restrict__ K,
                                         const float* __restrict__ T,
                                         const float* __restrict__ detT,
                                         float* __restrict__ Sign) {
  int gtid = blk * 256 + threadIdx.x;
  int gid = gtid >> 2;          // matrix id, < 131072
  int l = threadIdx.x & 3;      // quad lane = group id
  int k = gid & 15, m = (gid >> 4) & 63, n = (gid >> 10) & 63, b = gid >> 16;
  const float* qrow = Q + (b * 64 + n) * 16;
  const float* krow = K + (b * 64 + m) * 16;

  float qv[16];
#pragma unroll
  for (int i = 0; i < 16; ++i) qv[i] = qrow[i];

  float trace = 0.f, pq = 1.f, pk = 1.f;
#pragma unroll
  for (int i = 0; i < 16; ++i) {
    float kv = krow[i];
    pq *= qv[i]; pk *= kv;
    trace += qv[i] * kv * T[i * 272 + k];   // T[i,i,k]
  }
  float det = pq * pk * detT[k];

  // init in slope-0 config: slot s holds col (x=s, y=l), col index 4s+l
  v2f c0[8], c1[8], c2[8], c3[8];
  float nn0, nn1, nn2, nn3;
  {
    int j0 = l, j1 = 4 + l, j2 = 8 + l, j3 = 12 + l;
    float k0 = krow[j0], k1 = krow[j1], k2 = krow[j2], k3 = krow[j3];
#pragma unroll
    for (int i = 0; i < 8; ++i) {
      float qa = qv[2 * i], qb = qv[2 * i + 1];
      int ra = (2 * i) * 256, rb = (2 * i + 1) * 256;
      c0[i].x = qa * T[ra + j0 * 16 + k] * k0; c0[i].y = qb * T[rb + j0 * 16 + k] * k0;
      c1[i].x = qa * T[ra + j1 * 16 + k] * k1; c1[i].y = qb * T[rb + j1 * 16 + k] * k1;
      c2[i].x = qa * T[ra + j2 * 16 + k] * k2; c2[i].y = qb * T[rb + j2 * 16 + k] * k2;
      c3[i].x = qa * T[ra + j3 * 16 + k] * k3; c3[i].y = qb * T[rb + j3 * 16 + k] * k3;
    }
    v2f a0 = bc2(0.f), a1 = bc2(0.f), a2 = bc2(0.f), a3 = bc2(0.f);
#pragma unroll
    for (int i = 0; i < 8; ++i) {
      a0 = pkfma(c0[i], c0[i], a0);
      a1 = pkfma(c1[i], c1[i], a1);
      a2 = pkfma(c2[i], c2[i], a2);
      a3 = pkfma(c3[i], c3[i], a3);
    }
    nn0 = a0.x + a0.y; nn1 = a1.x + a1.y; nn2 = a2.x + a2.y; nn3 = a3.x + a3.y;
  }
  float d0 = 1.f, d1 = 1.f, d2 = 1.f, d3 = 1.f;
  float i0 = 1.f, i1 = 1.f, i2 = 1.f, i3 = 1.f;

  bool r1 = (l & 1) == 0;   // top role for delta=1
  bool r2 = (l & 2) == 0;   // top role for delta=2 and delta=3

#define INTRA6() { rot2(c0,c1,nn0,nn1,d0,i0,d1,i1); rot2(c2,c3,nn2,nn3,d2,i2,d3,i3); \
                   rot2(c0,c2,nn0,nn2,d0,i0,d2,i2); rot2(c1,c3,nn1,nn3,d1,i1,d3,i3); \
                   rot2(c0,c3,nn0,nn3,d0,i0,d3,i3); rot2(c1,c2,nn1,nn2,d1,i1,d2,i2); }

  for (int sw = 0; sw < SWEEPS; ++sw) {
    // cross-lane phases (same-x pairs), done in slope-0 layout
    xrot<0xB1>(c0, nn0, d0, i0, r1); xrot<0xB1>(c1, nn1, d1, i1, r1);
    xrot<0xB1>(c2, nn2, d2, i2, r1); xrot<0xB1>(c3, nn3, d3, i3, r1);
    xrot<0x4E>(c0, nn0, d0, i0, r2); xrot<0x4E>(c1, nn1, d1, i1, r2);
    xrot<0x4E>(c2, nn2, d2, i2, r2); xrot<0x4E>(c3, nn3, d3, i3, r2);
    xrot<0x1B>(c0, nn0, d0, i0, r2); xrot<0x1B>(c1, nn1, d1, i1, r2);
    xrot<0x1B>(c2, nn2, d2, i2, r2); xrot<0x1B>(c3, nn3, d3, i3, r2);

    INTRA6();                                   // slope 0
    tmov<0xB1>(c1, nn1, d1, i1); tmov<0x4E>(c2, nn2, d2, i2); tmov<0x1B>(c3, nn3, d3, i3);
    INTRA6();                                   // slope 1
    tmov<0x1B>(c1, nn1, d1, i1); tmov<0xB1>(c2, nn2, d2, i2); tmov<0x4E>(c3, nn3, d3, i3);
    INTRA6();                                   // slope 2
    tmov<0xB1>(c1, nn1, d1, i1); tmov<0x4E>(c2, nn2, d2, i2); tmov<0x1B>(c3, nn3, d3, i3);
    INTRA6();                                   // slope 3
    tmov<0x1B>(c1, nn1, d1, i1); tmov<0xB1>(c2, nn2, d2, i2); tmov<0x4E>(c3, nn3, d3, i3);

    if (sw < SWEEPS - 1) {
      // per-sweep rescale: fold scales into columns (bounds dynamic range)
      v2f s0 = bc2(d0), s1 = bc2(d1), s2 = bc2(d2), s3 = bc2(d3);
#pragma unroll
      for (int i = 0; i < 8; ++i) {
        c0[i] *= s0; c1[i] *= s1; c2[i] *= s2; c3[i] *= s3;
      }
      d0 = d1 = d2 = d3 = 1.f;
      i0 = i1 = i2 = i3 = 1.f;
    }
  }
#undef INTRA6

  // final norms: true sigma = d * ||stored col|| (last-sweep scales folded here)
  v2f a0 = bc2(0.f), a1 = bc2(0.f), a2 = bc2(0.f), a3 = bc2(0.f);
#pragma unroll
  for (int i = 0; i < 8; ++i) {
    a0 = pkfma(c0[i], c0[i], a0);
    a1 = pkfma(c1[i], c1[i], a1);
    a2 = pkfma(c2[i], c2[i], a2);
    a3 = pkfma(c3[i], c3[i], a3);
  }
  float s0 = d0 * fsqrt_fast(a0.x + a0.y), s1 = d1 * fsqrt_fast(a1.x + a1.y);
  float s2 = d2 * fsqrt_fast(a2.x + a2.y), s3 = d3 * fsqrt_fast(a3.x + a3.y);
  float lmin = fminf(fminf(s0, s1), fminf(s2, s3));
  float lmax = fmaxf(fmaxf(s0, s1), fmaxf(s2, s3));
  float lsum = __logf(s0 + EPSF) + __logf(s1 + EPSF) +
               __logf(s2 + EPSF) + __logf(s3 + EPSF);
  lmin = fminf(lmin, dppf<0xB1>(lmin));
  lmax = fmaxf(lmax, dppf<0xB1>(lmax));
  lsum += dppf<0xB1>(lsum);
  lmin = fminf(lmin, dppf<0x4E>(lmin));
  lmax = fmaxf(lmax, dppf<0x4E>(lmax));
  lsum += dppf<0x4E>(lsum);
  if (l == 0) {
    float* sp = Sign + (((b * 64 + n) * 64 + m) * 6) * 16 + k;
    sp[0]  = det;
    sp[16] = trace;
    sp[32] = lsum;
    sp[48] = lmin;
    sp[64] = lmax;
  }
}

// ---------------- rho quarter-product (packed, quad_perm broadcast) ----------------
template <int SRCL>
__device__ __forceinline__ void rho_quarter(v2f (&a)[4][8], v2f (&acc)[4][8]) {
  constexpr int CTRL = SRCL | (SRCL << 2) | (SRCL << 4) | (SRCL << 6);  // quad bcast
#pragma unroll
  for (int c = 0; c < 4; ++c) {        // global column kk = SRCL*4 + c
    v2f colk[8];
#pragma unroll
    for (int i = 0; i < 8; ++i) colk[i] = dpp2<CTRL>(a[c][i]);  // A[.][kk]
    constexpr int R = SRCL * 4;        // row base (c added below, both static)
#pragma unroll
    for (int jj = 0; jj < 4; ++jj) {
      int r = R + c;                   // static after unroll
      float f = (r & 1) ? a[jj][r >> 1].y : a[jj][r >> 1].x;  // A[kk][own col jj]
      v2f fv = bc2(f);
      if (SRCL == 0 && c == 0) {
#pragma unroll
        for (int i = 0; i < 8; ++i) acc[jj][i] = colk[i] * fv;   // first write: no init
      } else {
#pragma unroll
        for (int i = 0; i < 8; ++i) acc[jj][i] = pkfma(colk[i], fv, acc[jj][i]);
      }
    }
  }
}

// ---------------- rho body: feature 5 (spectral radius) ----------------
__device__ __forceinline__ void rho_body(int blk, const float* __restrict__ Q,
                                         const float* __restrict__ K,
                                         const float* __restrict__ T,
                                         float* __restrict__ Sign) {
  int gtid = blk * 256 + threadIdx.x;
  int gid = gtid >> 2;              // matrix id, < 131072
  int l = threadIdx.x & 3;
  int k = gid & 15, m = (gid >> 4) & 63, n = (gid >> 10) & 63, b = gid >> 16;
  const float* qrow = Q + (b * 64 + n) * 16;
  const float* krow = K + (b * 64 + m) * 16;

  v2f a[4][8];
#pragma unroll
  for (int jj = 0; jj < 4; ++jj) {
    int j = 4 * l + jj;
    float w = qrow[j] * krow[j];
#pragma unroll
    for (int i = 0; i < 8; ++i) {
      a[jj][i].x = T[(2 * i) * 256 + j * 16 + k] * w;
      a[jj][i].y = T[(2 * i + 1) * 256 + j * 16 + k] * w;
    }
  }

  // L = sum_{i<J} log(ss_i)*2^-(i+1) + log(ss_J)*2^-J (geometric tail)
  float L = 0.0f, wgt = 0.5f;
  for (int it = 0; it <= RHO_J; ++it) {
    v2f p0 = bc2(0.f), p1 = bc2(0.f), p2 = bc2(0.f), p3 = bc2(0.f);
#pragma unroll
    for (int i = 0; i < 8; ++i) {
      p0 = pkfma(a[0][i], a[0][i], p0);
      p1 = pkfma(a[1][i], a[1][i], p1);
      p2 = pkfma(a[2][i], a[2][i], p2);
      p3 = pkfma(a[3][i], a[3][i], p3);
    }
    v2f ps = (p0 + p1) + (p2 + p3);
    float ss = ps.x + ps.y;
    ss += dppf<0xB1>(ss);
    ss += dppf<0x4E>(ss);
    float w2 = (it == RHO_J) ? (wgt + wgt) : wgt;
    L = fmaf(__logf(ss), w2, L);
    wgt *= 0.5f;
    if (it == RHO_J) break;
    float s = (ss > 0.0f) ? frcp_fast(ss) : 0.0f;

    v2f acc[4][8];
    rho_quarter<0>(a, acc);   // first quarter writes acc (no zero-init)
    rho_quarter<1>(a, acc);
    rho_quarter<2>(a, acc);
    rho_quarter<3>(a, acc);

    v2f sv = bc2(s);
#pragma unroll
    for (int jj = 0; jj < 4; ++jj)
#pragma unroll
      for (int i = 0; i < 8; ++i) a[jj][i] = acc[jj][i] * sv;
  }
  float rho = __expf(L);
  if (l == 0) Sign[(((b * 64 + n) * 64 + m) * 6 + 5) * 16 + k] = rho;
}

// ---------------- merged main: svd blocks [0,2048) | rho blocks [2048,4096) ----------------
__global__ __launch_bounds__(256) void k_main(const float* __restrict__ Q,
                                              const float* __restrict__ K,
                                              const float* __restrict__ T,
                                              const float* __restrict__ detT,
                                              float* __restrict__ Sign) {
  int blk = blockIdx.x;
  if (blk < 2048) svd_body(blk, Q, K, T, detT, Sign);
  else            rho_body(blk - 2048, Q, K, T, Sign);
}

// ---------------- out[b,n,v] = sum_{m,s,k} Sign * V ----------------
__global__ __launch_bounds__(256) void k_out(const float* __restrict__ Sign,
                                             const float* __restrict__ V,
                                             float* __restrict__ out) {
  __shared__ float red[256];
  int bn = blockIdx.x;              // 0..127
  int b = bn >> 6;
  int t = threadIdx.x;
  int v = t & 15, mc = t >> 4;      // m in [mc*4, mc*4+4)
  const float* sp = Sign + bn * 6144;
  const float* vp = V + b * 98304;
  float acc = 0.f;
  for (int mm = 0; mm < 4; ++mm) {
    int m = mc * 4 + mm;
    const float* sr = sp + m * 96;
    const float* vr = vp + m * 1536 + v;
#pragma unroll
    for (int sk = 0; sk < 96; ++sk) acc = fmaf(sr[sk], vr[sk * 16], acc);
  }
  red[t] = acc;
  __syncthreads();
  for (int off = 128; off >= 16; off >>= 1) {
    if (t < off) red[t] += red[t + off];
    __syncthreads();
  }
  if (t < 16) out[bn * 16 + t] = red[t];
}

extern "C" void kernel_launch(void* const* d_in, const int* in_sizes, int n_in,
                              void* d_out, int out_size, void* d_ws, size_t ws_size,
                              hipStream_t stream) {
  const float* X  = (const float*)d_in[0];
  const float* Wk = (const float*)d_in[1];
  const float* Wq = (const float*)d_in[2];
  const float* T  = (const float*)d_in[3];
  const float* Wv = (const float*)d_in[4];
  float* out = (float*)d_out;
  float* ws = (float*)d_ws;

  float* Q    = ws + WS_Q;
  float* K    = ws + WS_K;
  float* detT = ws + WS_DETT;
  float* V    = ws + WS_V;
  float* Sign = ws + WS_SIGN;

  hipLaunchKernelGGL(k_setup, dim3(777),  dim3(256), 0, stream,
                     X, Wk, Wq, T, Wv, Q, K, detT, V);
  hipLaunchKernelGGL(k_main,  dim3(4096), dim3(256), 0, stream, Q, K, T, detT, Sign);
  hipLaunchKernelGGL(k_out,   dim3(128),  dim3(256), 0, stream, Sign, V, out);
}